// Round 1
// baseline (1329.564 us; speedup 1.0000x reference)
//
#include <hip/hip_runtime.h>
#include <math.h>

#define EMBED 384
#define HEADS 6
#define HD    64
#define SEQ   4096
#define BATCH 2
#define ROWS  (BATCH * SEQ)   // 8192
#define QKV_W (3 * EMBED)     // 1152

// ---------------------------------------------------------------------------
// LayerNorm: one wave (64 lanes) per row of 384. Each lane owns 6 elements
// (stride-64 -> coalesced). Wave-level butterfly reduce, no LDS, no barrier.
// ---------------------------------------------------------------------------
__global__ __launch_bounds__(64) void ln_kernel(const float* __restrict__ x,
                                                const float* __restrict__ g,
                                                const float* __restrict__ b,
                                                float* __restrict__ out) {
    const int row  = blockIdx.x;
    const int lane = threadIdx.x;
    const float* xr = x + (size_t)row * EMBED;

    float v[6];
    float sum = 0.f;
#pragma unroll
    for (int i = 0; i < 6; ++i) { v[i] = xr[lane + i * 64]; sum += v[i]; }
#pragma unroll
    for (int o = 32; o > 0; o >>= 1) sum += __shfl_xor(sum, o, 64);
    const float mu = sum * (1.f / EMBED);

    float var = 0.f;
#pragma unroll
    for (int i = 0; i < 6; ++i) { const float d = v[i] - mu; var += d * d; }
#pragma unroll
    for (int o = 32; o > 0; o >>= 1) var += __shfl_xor(var, o, 64);
    const float rstd = rsqrtf(var * (1.f / EMBED) + 1e-5f);

    float* orow = out + (size_t)row * EMBED;
#pragma unroll
    for (int i = 0; i < 6; ++i) {
        const int c = lane + i * 64;
        orow[c] = (v[i] - mu) * rstd * g[c] + b[c];
    }
}

// ---------------------------------------------------------------------------
// fp32 GEMM: C[M,N] = A[M,K] @ W[K,N] + bias (+residual | gelu)
// BM=BN=64, BK=16, 256 threads, 4x4 outputs/thread.
// As stored transposed [k][m] (stride 68), Ws [k][n] (stride 68):
//   compute reads are float4, bank-conflict-free / broadcast.
// EPI: 0 = bias only, 1 = bias + residual, 2 = bias + exact GELU
// ---------------------------------------------------------------------------
template <int EPI>
__global__ __launch_bounds__(256) void gemm_kernel(const float* __restrict__ A,
                                                   const float* __restrict__ W,
                                                   const float* __restrict__ bias,
                                                   const float* __restrict__ R,
                                                   float* __restrict__ C,
                                                   int M, int N, int K) {
    __shared__ float As[16][68];
    __shared__ float Ws[16][68];

    const int tid = threadIdx.x;
    const int m0 = blockIdx.x * 64;
    const int n0 = blockIdx.y * 64;
    const int rg = tid >> 4;   // 0..15 -> output rows 4*rg..+3
    const int cg = tid & 15;   // 0..15 -> output cols 4*cg..+3

    // cooperative-load indices
    const int lar = tid >> 2;          // A row in tile 0..63
    const int lac = (tid & 3) << 2;    // A col 0,4,8,12
    const int lwr = tid >> 4;          // W row 0..15
    const int lwc = (tid & 15) << 2;   // W col 0..60

    const float* Ap = A + (size_t)(m0 + lar) * K + lac;
    const float* Wp = W + (size_t)lwr * N + n0 + lwc;

    float acc[4][4] = {};

    for (int k0 = 0; k0 < K; k0 += 16) {
        const float4 av = *(const float4*)(Ap + k0);
        const float4 wv = *(const float4*)(Wp + (size_t)k0 * N);
        As[lac + 0][lar] = av.x;
        As[lac + 1][lar] = av.y;
        As[lac + 2][lar] = av.z;
        As[lac + 3][lar] = av.w;
        *(float4*)&Ws[lwr][lwc] = wv;
        __syncthreads();

#pragma unroll
        for (int kk = 0; kk < 16; ++kk) {
            const float4 a = *(const float4*)&As[kk][rg << 2];
            const float4 b4 = *(const float4*)&Ws[kk][cg << 2];
            const float aa[4] = {a.x, a.y, a.z, a.w};
            const float bb[4] = {b4.x, b4.y, b4.z, b4.w};
#pragma unroll
            for (int i = 0; i < 4; ++i)
#pragma unroll
                for (int j = 0; j < 4; ++j)
                    acc[i][j] = fmaf(aa[i], bb[j], acc[i][j]);
        }
        __syncthreads();
    }

#pragma unroll
    for (int i = 0; i < 4; ++i) {
        const int r = m0 + (rg << 2) + i;
        const int c = n0 + (cg << 2);
        const float4 bv = *(const float4*)(bias + c);
        float o[4] = {acc[i][0] + bv.x, acc[i][1] + bv.y,
                      acc[i][2] + bv.z, acc[i][3] + bv.w};
        if (EPI == 1) {
            const float4 rv = *(const float4*)(R + (size_t)r * N + c);
            o[0] += rv.x; o[1] += rv.y; o[2] += rv.z; o[3] += rv.w;
        } else if (EPI == 2) {
#pragma unroll
            for (int j = 0; j < 4; ++j)
                o[j] = 0.5f * o[j] * (1.f + erff(o[j] * 0.70710678118654752f));
        }
        *(float4*)(C + (size_t)r * N + c) = make_float4(o[0], o[1], o[2], o[3]);
    }
}

// ---------------------------------------------------------------------------
// Flash attention, fp32. One block = 64 q-rows of one (b,h). 256 threads.
// qkv layout: [B][N][H*192], head h: q at h*192, k at +64, v at +128.
// Online softmax over 64-key tiles; per-row stats wave-local (16-lane groups).
// ---------------------------------------------------------------------------
__global__ __launch_bounds__(256) void attn_kernel(const float* __restrict__ qkv,
                                                   float* __restrict__ msa) {
    const int qt = blockIdx.x;
    const int bh = blockIdx.y;
    const int b  = bh / HEADS;
    const int h  = bh % HEADS;
    const float* base = qkv + (size_t)b * SEQ * QKV_W + h * (3 * HD);
    const int q0 = qt * 64;

    __shared__ float QsT[64][68];  // [d][r], Q pre-scaled
    __shared__ float KsT[64][68];  // [d][j]
    __shared__ float Vs[64][68];   // [j][d]
    __shared__ float Ps[64][68];   // [r][j]

    const int tid = threadIdx.x;
    const int rg = tid >> 4;
    const int cg = tid & 15;
    const int lr  = tid >> 2;          // load row 0..63
    const int ld0 = (tid & 3) << 4;    // load col 0,16,32,48

    {   // load Q tile, fold in 1/sqrt(hd)
        const float* qp = base + (size_t)(q0 + lr) * QKV_W + ld0;
#pragma unroll
        for (int u = 0; u < 4; ++u) {
            const float4 q = *(const float4*)(qp + 4 * u);
            const int d = ld0 + 4 * u;
            QsT[d + 0][lr] = q.x * 0.125f;
            QsT[d + 1][lr] = q.y * 0.125f;
            QsT[d + 2][lr] = q.z * 0.125f;
            QsT[d + 3][lr] = q.w * 0.125f;
        }
    }

    float m_[4], l_[4], O[4][4];
#pragma unroll
    for (int i = 0; i < 4; ++i) {
        m_[i] = -INFINITY; l_[i] = 0.f;
#pragma unroll
        for (int c = 0; c < 4; ++c) O[i][c] = 0.f;
    }

    for (int t = 0; t < SEQ / 64; ++t) {
        const int j0 = t * 64;
        __syncthreads();  // previous PV done before K/V overwrite
        {
            const float* kp = base + (size_t)(j0 + lr) * QKV_W + HD + ld0;
            const float* vp = kp + HD;
#pragma unroll
            for (int u = 0; u < 4; ++u) {
                const int d = ld0 + 4 * u;
                const float4 kv = *(const float4*)(kp + 4 * u);
                KsT[d + 0][lr] = kv.x;
                KsT[d + 1][lr] = kv.y;
                KsT[d + 2][lr] = kv.z;
                KsT[d + 3][lr] = kv.w;
                *(float4*)&Vs[lr][d] = *(const float4*)(vp + 4 * u);
            }
        }
        __syncthreads();

        // S = Q @ K^T (scale already in Q)
        float s[4][4] = {};
#pragma unroll 8
        for (int d = 0; d < 64; ++d) {
            const float4 q = *(const float4*)&QsT[d][rg << 2];
            const float4 k = *(const float4*)&KsT[d][cg << 2];
            const float qa[4] = {q.x, q.y, q.z, q.w};
            const float ka[4] = {k.x, k.y, k.z, k.w};
#pragma unroll
            for (int i = 0; i < 4; ++i)
#pragma unroll
                for (int j = 0; j < 4; ++j)
                    s[i][j] = fmaf(qa[i], ka[j], s[i][j]);
        }

        // online softmax (rows 4*rg..+3, stats shared across the 16-lane group)
#pragma unroll
        for (int i = 0; i < 4; ++i) {
            float pm = fmaxf(fmaxf(s[i][0], s[i][1]), fmaxf(s[i][2], s[i][3]));
#pragma unroll
            for (int o = 1; o < 16; o <<= 1)
                pm = fmaxf(pm, __shfl_xor(pm, o, 64));
            const float mn = fmaxf(m_[i], pm);
            const float f = __expf(m_[i] - mn);
            m_[i] = mn;
            float rs = 0.f;
#pragma unroll
            for (int j = 0; j < 4; ++j) {
                const float p = __expf(s[i][j] - mn);
                s[i][j] = p;
                rs += p;
            }
#pragma unroll
            for (int o = 1; o < 16; o <<= 1)
                rs += __shfl_xor(rs, o, 64);
            l_[i] = l_[i] * f + rs;
#pragma unroll
            for (int c = 0; c < 4; ++c) O[i][c] *= f;
        }

        // stash P tile
#pragma unroll
        for (int i = 0; i < 4; ++i)
            *(float4*)&Ps[(rg << 2) + i][cg << 2] =
                make_float4(s[i][0], s[i][1], s[i][2], s[i][3]);
        __syncthreads();

        // O += P @ V
#pragma unroll 8
        for (int j = 0; j < 64; ++j) {
            const float4 v = *(const float4*)&Vs[j][cg << 2];
            const float va[4] = {v.x, v.y, v.z, v.w};
#pragma unroll
            for (int i = 0; i < 4; ++i) {
                const float p = Ps[(rg << 2) + i][j];
#pragma unroll
                for (int c = 0; c < 4; ++c)
                    O[i][c] = fmaf(p, va[c], O[i][c]);
            }
        }
    }

    // normalize + write out to (B, N, E) with E index = h*64 + d
#pragma unroll
    for (int i = 0; i < 4; ++i) {
        const float inv = 1.f / l_[i];
        const int r = q0 + (rg << 2) + i;
        const float4 o = make_float4(O[i][0] * inv, O[i][1] * inv,
                                     O[i][2] * inv, O[i][3] * inv);
        *(float4*)(msa + (size_t)(b * SEQ + r) * EMBED + h * HD + (cg << 2)) = o;
    }
}

// ---------------------------------------------------------------------------
extern "C" void kernel_launch(void* const* d_in, const int* in_sizes, int n_in,
                              void* d_out, int out_size, void* d_ws, size_t ws_size,
                              hipStream_t stream) {
    const float* x     = (const float*)d_in[0];
    const float* w_qkv = (const float*)d_in[1];
    const float* b_qkv = (const float*)d_in[2];
    const float* w_lin = (const float*)d_in[3];
    const float* b_lin = (const float*)d_in[4];
    const float* g1    = (const float*)d_in[5];
    const float* be1   = (const float*)d_in[6];
    const float* g2    = (const float*)d_in[7];
    const float* be2   = (const float*)d_in[8];
    const float* w1    = (const float*)d_in[9];
    const float* b1    = (const float*)d_in[10];
    const float* w2    = (const float*)d_in[11];
    const float* b2    = (const float*)d_in[12];
    float* out = (float*)d_out;

    // workspace carve-up (floats): h/h2 | qkv~hidden | msa | x2  => ~88 MB
    float* h_buf = (float*)d_ws;
    float* big   = h_buf + (size_t)ROWS * EMBED;        // max(1152,1536) cols
    float* msa   = big   + (size_t)ROWS * 4 * EMBED;
    float* x2    = msa   + (size_t)ROWS * EMBED;

    // 1) h = LN1(x)
    ln_kernel<<<ROWS, 64, 0, stream>>>(x, g1, be1, h_buf);
    // 2) qkv = h @ w_qkv + b_qkv
    gemm_kernel<0><<<dim3(ROWS / 64, QKV_W / 64), 256, 0, stream>>>(
        h_buf, w_qkv, b_qkv, nullptr, big, ROWS, QKV_W, EMBED);
    // 3) msa = attention(qkv)
    attn_kernel<<<dim3(SEQ / 64, BATCH * HEADS), 256, 0, stream>>>(big, msa);
    // 4) x2 = msa @ w_lin + b_lin + x
    gemm_kernel<1><<<dim3(ROWS / 64, EMBED / 64), 256, 0, stream>>>(
        msa, w_lin, b_lin, x, x2, ROWS, EMBED, EMBED);
    // 5) h2 = LN2(x2)
    ln_kernel<<<ROWS, 64, 0, stream>>>(x2, g2, be2, h_buf);
    // 6) hidden = gelu(h2 @ w1 + b1)
    gemm_kernel<2><<<dim3(ROWS / 64, (4 * EMBED) / 64), 256, 0, stream>>>(
        h_buf, w1, b1, nullptr, big, ROWS, 4 * EMBED, EMBED);
    // 7) out = hidden @ w2 + b2 + x2
    gemm_kernel<1><<<dim3(ROWS / 64, EMBED / 64), 256, 0, stream>>>(
        big, w2, b2, x2, out, ROWS, EMBED, 4 * EMBED);
}

// Round 2
// 673.916 us; speedup vs baseline: 1.9729x; 1.9729x over previous
//
#include <hip/hip_runtime.h>
#include <math.h>

#define EMBED 384
#define HEADS 6
#define HD    64
#define SEQ   4096
#define BATCH 2
#define ROWS  (BATCH * SEQ)   // 8192
#define QKV_W (3 * EMBED)     // 1152

typedef __bf16 bf16x8 __attribute__((ext_vector_type(8)));
typedef float  f32x16 __attribute__((ext_vector_type(16)));
typedef unsigned short ushort_t;

union U4B { uint4 u; bf16x8 b; };

#define MFMA(a, b, c) __builtin_amdgcn_mfma_f32_32x32x16_bf16(a, b, c, 0, 0, 0)

__device__ __forceinline__ unsigned short bfbits(float f) {
    return __builtin_bit_cast(unsigned short, (__bf16)f);
}
__device__ __forceinline__ unsigned pack2(float a, float b) {
    return ((unsigned)bfbits(b) << 16) | (unsigned)bfbits(a);
}

// ---------------------------------------------------------------------------
// LayerNorm: one wave per row of 384.
// ---------------------------------------------------------------------------
__global__ __launch_bounds__(64) void ln_kernel(const float* __restrict__ x,
                                                const float* __restrict__ g,
                                                const float* __restrict__ b,
                                                float* __restrict__ out) {
    const int row  = blockIdx.x;
    const int lane = threadIdx.x;
    const float* xr = x + (size_t)row * EMBED;

    float v[6];
    float sum = 0.f;
#pragma unroll
    for (int i = 0; i < 6; ++i) { v[i] = xr[lane + i * 64]; sum += v[i]; }
#pragma unroll
    for (int o = 32; o > 0; o >>= 1) sum += __shfl_xor(sum, o, 64);
    const float mu = sum * (1.f / EMBED);

    float var = 0.f;
#pragma unroll
    for (int i = 0; i < 6; ++i) { const float d = v[i] - mu; var += d * d; }
#pragma unroll
    for (int o = 32; o > 0; o >>= 1) var += __shfl_xor(var, o, 64);
    const float rstd = rsqrtf(var * (1.f / EMBED) + 1e-5f);

    float* orow = out + (size_t)row * EMBED;
#pragma unroll
    for (int i = 0; i < 6; ++i) {
        const int c = lane + i * 64;
        orow[c] = (v[i] - mu) * rstd * g[c] + b[c];
    }
}

// ---------------------------------------------------------------------------
// fp32 GEMM (unchanged from passing baseline).
// EPI: 0 = bias, 1 = bias+residual, 2 = bias+exact GELU
// ---------------------------------------------------------------------------
template <int EPI>
__global__ __launch_bounds__(256) void gemm_kernel(const float* __restrict__ A,
                                                   const float* __restrict__ W,
                                                   const float* __restrict__ bias,
                                                   const float* __restrict__ R,
                                                   float* __restrict__ C,
                                                   int M, int N, int K) {
    __shared__ float As[16][68];
    __shared__ float Ws[16][68];

    const int tid = threadIdx.x;
    const int m0 = blockIdx.x * 64;
    const int n0 = blockIdx.y * 64;
    const int rg = tid >> 4;
    const int cg = tid & 15;

    const int lar = tid >> 2;
    const int lac = (tid & 3) << 2;
    const int lwr = tid >> 4;
    const int lwc = (tid & 15) << 2;

    const float* Ap = A + (size_t)(m0 + lar) * K + lac;
    const float* Wp = W + (size_t)lwr * N + n0 + lwc;

    float acc[4][4] = {};

    for (int k0 = 0; k0 < K; k0 += 16) {
        const float4 av = *(const float4*)(Ap + k0);
        const float4 wv = *(const float4*)(Wp + (size_t)k0 * N);
        As[lac + 0][lar] = av.x;
        As[lac + 1][lar] = av.y;
        As[lac + 2][lar] = av.z;
        As[lac + 3][lar] = av.w;
        *(float4*)&Ws[lwr][lwc] = wv;
        __syncthreads();

#pragma unroll
        for (int kk = 0; kk < 16; ++kk) {
            const float4 a = *(const float4*)&As[kk][rg << 2];
            const float4 b4 = *(const float4*)&Ws[kk][cg << 2];
            const float aa[4] = {a.x, a.y, a.z, a.w};
            const float bb[4] = {b4.x, b4.y, b4.z, b4.w};
#pragma unroll
            for (int i = 0; i < 4; ++i)
#pragma unroll
                for (int j = 0; j < 4; ++j)
                    acc[i][j] = fmaf(aa[i], bb[j], acc[i][j]);
        }
        __syncthreads();
    }

#pragma unroll
    for (int i = 0; i < 4; ++i) {
        const int r = m0 + (rg << 2) + i;
        const int c = n0 + (cg << 2);
        const float4 bv = *(const float4*)(bias + c);
        float o[4] = {acc[i][0] + bv.x, acc[i][1] + bv.y,
                      acc[i][2] + bv.z, acc[i][3] + bv.w};
        if (EPI == 1) {
            const float4 rv = *(const float4*)(R + (size_t)r * N + c);
            o[0] += rv.x; o[1] += rv.y; o[2] += rv.z; o[3] += rv.w;
        } else if (EPI == 2) {
#pragma unroll
            for (int j = 0; j < 4; ++j)
                o[j] = 0.5f * o[j] * (1.f + erff(o[j] * 0.70710678118654752f));
        }
        *(float4*)(C + (size_t)r * N + c) = make_float4(o[0], o[1], o[2], o[3]);
    }
}

// ---------------------------------------------------------------------------
// Prep: qkv fp32 [B][N][H*192] -> Qbf (x0.125) [bh][N][64], Kbf [bh][N][64],
// Vt [bh][64][N]  (all bf16 as ushort)
// ---------------------------------------------------------------------------
__global__ __launch_bounds__(256) void qkv_prep(const float* __restrict__ qkvf,
                                                ushort_t* __restrict__ qb,
                                                ushort_t* __restrict__ kb,
                                                ushort_t* __restrict__ vt) {
    __shared__ ushort_t vs[64][72];
    const int nt = blockIdx.x, bh = blockIdx.y;
    const int b = bh / HEADS, h = bh % HEADS;
    const int tid = threadIdx.x;
    const int r = tid >> 2, c0 = (tid & 3) * 16;
    const int n0 = nt * 64;
    const float* src = qkvf + (size_t)(b * SEQ + n0 + r) * QKV_W + h * 192;

    union { ushort_t s[16]; uint4 u[2]; } tq, tk;
#pragma unroll
    for (int i = 0; i < 16; ++i) {
        tq.s[i] = bfbits(src[c0 + i] * 0.125f);
        tk.s[i] = bfbits(src[64 + c0 + i]);
        vs[r][c0 + i] = bfbits(src[128 + c0 + i]);
    }
    uint4* qdst = (uint4*)(qb + ((size_t)bh * SEQ + n0 + r) * 64 + c0);
    uint4* kdst = (uint4*)(kb + ((size_t)bh * SEQ + n0 + r) * 64 + c0);
    qdst[0] = tq.u[0]; qdst[1] = tq.u[1];
    kdst[0] = tk.u[0]; kdst[1] = tk.u[1];
    __syncthreads();

#pragma unroll
    for (int u = 0; u < 2; ++u) {
        const int cid = tid * 2 + u;       // 0..511
        const int d = cid >> 3, cc = cid & 7;
        union { ushort_t s[8]; uint4 u4; } ov;
#pragma unroll
        for (int jj = 0; jj < 8; ++jj) ov.s[jj] = vs[cc * 8 + jj][d];
        *(uint4*)(vt + (size_t)bh * 64 * SEQ + (size_t)d * SEQ + n0 + cc * 8) = ov.u4;
    }
}

// ---------------------------------------------------------------------------
// Flash attention, bf16 MFMA (32x32x16), swapped-QK form.
// 256 threads = 4 warps; warp owns 32 q-rows; block = 128 q-rows; KVBLK = 64.
// S^T = mfma(K, Q): lane owns q = lane&31; its 16 regs/chunk hold keys
// (r&3)+8*(r>>2)+4*h (h = lane>>5). Softmax lane-local + shfl_xor(32).
// PV: O^T = mfma(V^T, P^T), P^T fragments assembled in-register via 2 shfl.
// ---------------------------------------------------------------------------
__global__ __launch_bounds__(256) void attn_kernel(const ushort_t* __restrict__ qb,
                                                   const ushort_t* __restrict__ kb,
                                                   const ushort_t* __restrict__ vt,
                                                   float* __restrict__ msa) {
    __shared__ __align__(16) char smem_raw[34816];
    uint4* kbl = (uint4*)smem_raw;              // 2 x 512 uint4 (16 KB)
    uint4* vbl = (uint4*)(smem_raw + 16384);    // 2 x 512 uint4 (16 KB)

    const int tid = threadIdx.x;
    const int lq = tid & 31;           // q within warp tile / row within chunk
    const int h  = (tid >> 5) & 1;     // half-lane
    const int w  = tid >> 6;           // warp
    const int bh = blockIdx.y;
    const int q0 = blockIdx.x * 128 + w * 32;

    const ushort_t* kg = kb + (size_t)bh * SEQ * 64;
    const ushort_t* vg = vt + (size_t)bh * 64 * SEQ;

    // Q fragments (B-operand): lane holds Q[q0+lq][16s + 8h + j]
    U4B qf[4];
    {
        const uint4* qrow = (const uint4*)(qb + ((size_t)bh * SEQ + q0 + lq) * 64);
#pragma unroll
        for (int s = 0; s < 4; ++s) qf[s].u = qrow[2 * s + h];
    }

    f32x16 o[2];
#pragma unroll
    for (int dc = 0; dc < 2; ++dc)
#pragma unroll
        for (int r = 0; r < 16; ++r) o[dc][r] = 0.f;
    float m_run = -INFINITY, l_run = 0.f;

    uint4 nk[2], nv[2];
    auto load_tile = [&](int t) {
#pragma unroll
        for (int u = 0; u < 2; ++u) {
            const int cid = tid * 2 + u;
            const int row = cid >> 3, c = cid & 7;
            nk[u] = *(const uint4*)(kg + (size_t)(t * 64 + row) * 64 + c * 8);
            nv[u] = *(const uint4*)(vg + (size_t)row * SEQ + t * 64 + c * 8);
        }
    };
    auto write_tile = [&](int buf) {
#pragma unroll
        for (int u = 0; u < 2; ++u) {
            const int cid = tid * 2 + u;
            const int row = cid >> 3, c = cid & 7;
            const int idx = buf * 512 + row * 8 + (c ^ (row & 7));
            kbl[idx] = nk[u];
            vbl[idx] = nv[u];
        }
    };

    load_tile(0);
    write_tile(0);

    for (int t = 0; t < SEQ / 64; ++t) {
        const int tn = (t + 1 < SEQ / 64) ? t + 1 : t;
        load_tile(tn);                 // issue next-tile loads early (T14)
        __syncthreads();               // current buffer visible
        const int bs = (t & 1) * 512;

        // ---- S^T = K . Q^T  (2 chunks of 32 keys) ----
        f32x16 st[2];
#pragma unroll
        for (int kc = 0; kc < 2; ++kc) {
#pragma unroll
            for (int r = 0; r < 16; ++r) st[kc][r] = 0.f;
#pragma unroll
            for (int s = 0; s < 4; ++s) {
                const int row = kc * 32 + lq;
                U4B ka; ka.u = kbl[bs + row * 8 + ((2 * s + h) ^ (row & 7))];
                st[kc] = MFMA(ka.b, qf[s].b, st[kc]);
            }
        }

        // ---- online softmax (lane-local 32 keys + partner 32) ----
        float pm = st[0][0];
#pragma unroll
        for (int r = 1; r < 16; ++r) pm = fmaxf(pm, st[0][r]);
#pragma unroll
        for (int r = 0; r < 16; ++r) pm = fmaxf(pm, st[1][r]);
        pm = fmaxf(pm, __shfl_xor(pm, 32));
        const float mn = fmaxf(m_run, pm);
        const float f = __expf(m_run - mn);
        m_run = mn;

        float rs = 0.f;
#pragma unroll
        for (int kc = 0; kc < 2; ++kc)
#pragma unroll
            for (int r = 0; r < 16; ++r) {
                const float p = __expf(st[kc][r] - mn);
                st[kc][r] = p;
                rs += p;
            }
        rs += __shfl_xor(rs, 32);
        l_run = l_run * f + rs;
#pragma unroll
        for (int dc = 0; dc < 2; ++dc)
#pragma unroll
            for (int r = 0; r < 16; ++r) o[dc][r] *= f;

        // ---- pack P to bf16 pairs ----
        unsigned pk[2][8];
#pragma unroll
        for (int kc = 0; kc < 2; ++kc)
#pragma unroll
            for (int m = 0; m < 8; ++m)
                pk[kc][m] = pack2(st[kc][2 * m], st[kc][2 * m + 1]);

        // ---- O^T += V^T . P^T ----
#pragma unroll
        for (int ks = 0; ks < 4; ++ks) {
            const int kc = ks >> 1;
            const int A0 = 4 * (ks & 1);
            const unsigned c0 = pk[kc][A0 + 0], c1 = pk[kc][A0 + 1];
            const unsigned c2 = pk[kc][A0 + 2], c3 = pk[kc][A0 + 3];
            const unsigned s0 = h ? c0 : c2;
            const unsigned s1 = h ? c1 : c3;
            const unsigned r0 = (unsigned)__shfl_xor((int)s0, 32);
            const unsigned r1 = (unsigned)__shfl_xor((int)s1, 32);
            U4B fb;
            fb.u.x = h ? r0 : c0;
            fb.u.y = h ? r1 : c1;
            fb.u.z = h ? c2 : r0;
            fb.u.w = h ? c3 : r1;
#pragma unroll
            for (int dc = 0; dc < 2; ++dc) {
                const int row = dc * 32 + lq;
                U4B va; va.u = vbl[bs + row * 8 + ((2 * ks + h) ^ (row & 7))];
                o[dc] = MFMA(va.b, fb.b, o[dc]);
            }
        }

        write_tile((t + 1) & 1);       // safe: separated by this iter's barrier
    }

    // ---- epilogue: normalize, LDS transpose, coalesced store ----
    __syncthreads();
    float* ob = (float*)smem_raw;      // [4][32][68]
    const float inv = 1.f / l_run;
#pragma unroll
    for (int dc = 0; dc < 2; ++dc)
#pragma unroll
        for (int r = 0; r < 16; ++r) {
            const int d = (r & 3) + 8 * (r >> 2) + 4 * h + 32 * dc;
            ob[(w * 32 + lq) * 68 + d] = o[dc][r] * inv;
        }
    __syncthreads();

    const int b = bh / HEADS, hh = bh % HEADS;
    const int w2 = tid >> 6, l2 = tid & 63;
    const int qr = l2 >> 1, half = (l2 & 1) * 32;
    float* dst = msa + ((size_t)(b * SEQ) + blockIdx.x * 128 + w2 * 32 + qr) * EMBED
                 + hh * 64 + half;
    const float* srcp = &ob[(w2 * 32 + qr) * 68 + half];
#pragma unroll
    for (int j = 0; j < 8; ++j)
        *(float4*)(dst + 4 * j) = *(const float4*)(srcp + 4 * j);
}

// ---------------------------------------------------------------------------
extern "C" void kernel_launch(void* const* d_in, const int* in_sizes, int n_in,
                              void* d_out, int out_size, void* d_ws, size_t ws_size,
                              hipStream_t stream) {
    const float* x     = (const float*)d_in[0];
    const float* w_qkv = (const float*)d_in[1];
    const float* b_qkv = (const float*)d_in[2];
    const float* w_lin = (const float*)d_in[3];
    const float* b_lin = (const float*)d_in[4];
    const float* g1    = (const float*)d_in[5];
    const float* be1   = (const float*)d_in[6];
    const float* g2    = (const float*)d_in[7];
    const float* be2   = (const float*)d_in[8];
    const float* w1    = (const float*)d_in[9];
    const float* b1    = (const float*)d_in[10];
    const float* w2    = (const float*)d_in[11];
    const float* b2    = (const float*)d_in[12];
    float* out = (float*)d_out;

    // workspace carve-up (same 88.1 MB footprint as baseline):
    // h_buf [12.58MB] | big [50.33MB] | msa [12.58MB] | x2 [12.58MB]
    // overlays: Qbf+Kbf over h_buf (dead after qkv GEMM); Vt over x2 (written later)
    float* h_buf = (float*)d_ws;
    float* big   = h_buf + (size_t)ROWS * EMBED;
    float* msa   = big   + (size_t)ROWS * 4 * EMBED;
    float* x2    = msa   + (size_t)ROWS * EMBED;
    ushort_t* qbf = (ushort_t*)h_buf;
    ushort_t* kbf = qbf + (size_t)BATCH * HEADS * SEQ * 64;
    ushort_t* vt  = (ushort_t*)x2;

    // 1) h = LN1(x)
    ln_kernel<<<ROWS, 64, 0, stream>>>(x, g1, be1, h_buf);
    // 2) qkv = h @ w_qkv + b_qkv   (fp32, into big)
    gemm_kernel<0><<<dim3(ROWS / 64, QKV_W / 64), 256, 0, stream>>>(
        h_buf, w_qkv, b_qkv, nullptr, big, ROWS, QKV_W, EMBED);
    // 2.5) bf16 prep (overwrites h_buf region + vt region)
    qkv_prep<<<dim3(SEQ / 64, BATCH * HEADS), 256, 0, stream>>>(big, qbf, kbf, vt);
    // 3) msa = attention(Qbf, Kbf, Vt)
    attn_kernel<<<dim3(SEQ / 128, BATCH * HEADS), 256, 0, stream>>>(qbf, kbf, vt, msa);
    // 4) x2 = msa @ w_lin + b_lin + x   (clobbers vt region: attn already done)
    gemm_kernel<1><<<dim3(ROWS / 64, EMBED / 64), 256, 0, stream>>>(
        msa, w_lin, b_lin, x, x2, ROWS, EMBED, EMBED);
    // 5) h2 = LN2(x2)
    ln_kernel<<<ROWS, 64, 0, stream>>>(x2, g2, be2, h_buf);
    // 6) hidden = gelu(h2 @ w1 + b1)
    gemm_kernel<2><<<dim3(ROWS / 64, (4 * EMBED) / 64), 256, 0, stream>>>(
        h_buf, w1, b1, nullptr, big, ROWS, 4 * EMBED, EMBED);
    // 7) out = hidden @ w2 + b2 + x2
    gemm_kernel<1><<<dim3(ROWS / 64, EMBED / 64), 256, 0, stream>>>(
        big, w2, b2, x2, out, ROWS, EMBED, 4 * EMBED);
}

// Round 3
// 517.624 us; speedup vs baseline: 2.5686x; 1.3019x over previous
//
#include <hip/hip_runtime.h>
#include <math.h>

#define EMBED 384
#define HEADS 6
#define HD    64
#define SEQ   4096
#define BATCH 2
#define ROWS  (BATCH * SEQ)   // 8192
#define QKV_W (3 * EMBED)     // 1152

typedef __bf16 bf16x8 __attribute__((ext_vector_type(8)));
typedef float  f32x16 __attribute__((ext_vector_type(16)));
typedef unsigned short ushort_t;

union U4B { uint4 u; bf16x8 b; };

#define MFMA(a, b, c) __builtin_amdgcn_mfma_f32_32x32x16_bf16(a, b, c, 0, 0, 0)

__device__ __forceinline__ unsigned short bfbits(float f) {
    return __builtin_bit_cast(unsigned short, (__bf16)f);
}
__device__ __forceinline__ unsigned pack2(float a, float b) {
    return ((unsigned)bfbits(b) << 16) | (unsigned)bfbits(a);
}

// ---------------------------------------------------------------------------
// LayerNorm: one wave per row of 384, bf16 output.
// ---------------------------------------------------------------------------
__global__ __launch_bounds__(64) void ln_kernel(const float* __restrict__ x,
                                                const float* __restrict__ g,
                                                const float* __restrict__ b,
                                                ushort_t* __restrict__ out) {
    const int row  = blockIdx.x;
    const int lane = threadIdx.x;
    const float* xr = x + (size_t)row * EMBED;

    float v[6];
    float sum = 0.f;
#pragma unroll
    for (int i = 0; i < 6; ++i) { v[i] = xr[lane + i * 64]; sum += v[i]; }
#pragma unroll
    for (int o = 32; o > 0; o >>= 1) sum += __shfl_xor(sum, o, 64);
    const float mu = sum * (1.f / EMBED);

    float var = 0.f;
#pragma unroll
    for (int i = 0; i < 6; ++i) { const float d = v[i] - mu; var += d * d; }
#pragma unroll
    for (int o = 32; o > 0; o >>= 1) var += __shfl_xor(var, o, 64);
    const float rstd = rsqrtf(var * (1.f / EMBED) + 1e-5f);

    ushort_t* orow = out + (size_t)row * EMBED;
#pragma unroll
    for (int i = 0; i < 6; ++i) {
        const int c = lane + i * 64;
        orow[c] = bfbits((v[i] - mu) * rstd * g[c] + b[c]);
    }
}

// ---------------------------------------------------------------------------
// Weight transpose+convert: W fp32 [K][N] -> Wt bf16 [N][K]
// ---------------------------------------------------------------------------
__global__ __launch_bounds__(256) void wcvt(const float* __restrict__ W,
                                            ushort_t* __restrict__ Wt,
                                            int K, int N) {
    __shared__ float ws[32][33];
    const int nb = blockIdx.x * 32, kb = blockIdx.y * 32;
    const int tid = threadIdx.x;
    {
        const int r = tid >> 3, c = (tid & 7) * 4;
        const float4 v = *(const float4*)(W + (size_t)(kb + r) * N + nb + c);
        ws[r][c] = v.x; ws[r][c + 1] = v.y; ws[r][c + 2] = v.z; ws[r][c + 3] = v.w;
    }
    __syncthreads();
    const int n = tid >> 3, k0 = (tid & 7) * 4;
    union { ushort_t s[4]; uint2 u; } o;
#pragma unroll
    for (int i = 0; i < 4; ++i) o.s[i] = bfbits(ws[k0 + i][n]);
    *(uint2*)(Wt + (size_t)(nb + n) * K + kb + k0) = o.u;
}

// ---------------------------------------------------------------------------
// bf16 MFMA GEMM: C = A[M,K] @ Bt^T + bias, 128x128 tile, BK=64, 4 waves,
// reg-staged double-buffered LDS with ch^(row&7) swizzle, 1 barrier/step.
// EPI 0: QKV split-write (q*0.125, k, v) bf16; EPI 1: fp32 out + residual;
// EPI 2: bf16 out + exact GELU.
// ---------------------------------------------------------------------------
template <int EPI>
__global__ __launch_bounds__(256) void gemm_bf16(const ushort_t* __restrict__ A,
                                                 const ushort_t* __restrict__ Bt,
                                                 const float* __restrict__ bias,
                                                 const float* __restrict__ R,
                                                 float* __restrict__ C,
                                                 ushort_t* __restrict__ Hb,
                                                 ushort_t* __restrict__ qb,
                                                 ushort_t* __restrict__ kb,
                                                 ushort_t* __restrict__ vr,
                                                 int N, int K) {
    __shared__ uint4 asl[2048];   // 2 x [128 rows][8 chunks] swizzled
    __shared__ uint4 bsl[2048];

    const int tid = threadIdx.x;
    const int lq = tid & 31;
    const int h  = (tid >> 5) & 1;
    const int w  = tid >> 6;
    const int wr = w >> 1, wc = w & 1;
    const int m0 = blockIdx.x * 128;
    const int n0 = blockIdx.y * 128;

    f32x16 acc[2][2];
#pragma unroll
    for (int a = 0; a < 2; ++a)
#pragma unroll
        for (int b = 0; b < 2; ++b)
#pragma unroll
            for (int r = 0; r < 16; ++r) acc[a][b][r] = 0.f;

    uint4 ra[4], rb[4];
    auto load_regs = [&](int s) {
        const int k0 = s * 64;
#pragma unroll
        for (int u = 0; u < 4; ++u) {
            const int ci = tid + 256 * u;
            const int row = ci >> 3, ch = ci & 7;
            ra[u] = *(const uint4*)(A + (size_t)(m0 + row) * K + k0 + ch * 8);
            rb[u] = *(const uint4*)(Bt + (size_t)(n0 + row) * K + k0 + ch * 8);
        }
    };
    auto write_lds = [&](int buf) {
#pragma unroll
        for (int u = 0; u < 4; ++u) {
            const int ci = tid + 256 * u;
            const int row = ci >> 3, ch = ci & 7;
            const int idx = buf * 1024 + row * 8 + (ch ^ (row & 7));
            asl[idx] = ra[u];
            bsl[idx] = rb[u];
        }
    };

    load_regs(0);
    write_lds(0);
    const int nst = K / 64;
    for (int s = 0; s < nst; ++s) {
        if (s + 1 < nst) load_regs(s + 1);
        __syncthreads();
        const int bs = (s & 1) * 1024;
#pragma unroll
        for (int ks = 0; ks < 4; ++ks) {
            U4B af[2], bf[2];
#pragma unroll
            for (int a = 0; a < 2; ++a) {
                const int rm = wr * 64 + a * 32 + lq;
                af[a].u = asl[bs + rm * 8 + ((2 * ks + h) ^ (rm & 7))];
                const int rn = wc * 64 + a * 32 + lq;
                bf[a].u = bsl[bs + rn * 8 + ((2 * ks + h) ^ (rn & 7))];
            }
#pragma unroll
            for (int a = 0; a < 2; ++a)
#pragma unroll
                for (int b = 0; b < 2; ++b)
                    acc[a][b] = MFMA(af[a].b, bf[b].b, acc[a][b]);
        }
        if (s + 1 < nst) write_lds((s + 1) & 1);
    }

    // ---- epilogue ----
#pragma unroll
    for (int a = 0; a < 2; ++a)
#pragma unroll
        for (int b = 0; b < 2; ++b) {
            const int Cb = n0 + wc * 64 + b * 32;
            const int c = Cb + lq;
            const float bv = bias[c];
            if (EPI == 0) {
                const int head = Cb / 192, rem = Cb % 192;
                const int role = rem >> 6, d = (rem & 63) + lq;
#pragma unroll
                for (int r = 0; r < 16; ++r) {
                    const int grow = m0 + wr * 64 + a * 32 + (r & 3) + 8 * (r >> 2) + 4 * h;
                    const int bat = grow >> 12, n = grow & 4095;
                    const size_t idx = ((size_t)(bat * HEADS + head) * SEQ + n) * 64 + d;
                    const float v = acc[a][b][r] + bv;
                    if (role == 0)      qb[idx] = bfbits(v * 0.125f);
                    else if (role == 1) kb[idx] = bfbits(v);
                    else                vr[idx] = bfbits(v);
                }
            } else {
#pragma unroll
                for (int r = 0; r < 16; ++r) {
                    const int row = m0 + wr * 64 + a * 32 + (r & 3) + 8 * (r >> 2) + 4 * h;
                    const float v = acc[a][b][r] + bv;
                    if (EPI == 1) {
                        C[(size_t)row * N + c] = v + R[(size_t)row * N + c];
                    } else {
                        const float gl = 0.5f * v * (1.f + erff(v * 0.70710678118654752f));
                        Hb[(size_t)row * N + c] = bfbits(gl);
                    }
                }
            }
        }
}

// ---------------------------------------------------------------------------
// V transpose: vr [bh][seq][64] bf16 -> vt [bh][64][seq] bf16
// ---------------------------------------------------------------------------
__global__ __launch_bounds__(256) void vtrans(const ushort_t* __restrict__ vr,
                                              ushort_t* __restrict__ vt) {
    __shared__ ushort_t vs[64][72];
    const int nt = blockIdx.x, bh = blockIdx.y;
    const int tid = threadIdx.x;
    const int r = tid >> 2, c0 = (tid & 3) * 16;
    const int n0 = nt * 64;
    {
        const uint4* src = (const uint4*)(vr + ((size_t)bh * SEQ + n0 + r) * 64 + c0);
        union { uint4 u[2]; ushort_t s[16]; } t2;
        t2.u[0] = src[0]; t2.u[1] = src[1];
#pragma unroll
        for (int i = 0; i < 16; ++i) vs[r][c0 + i] = t2.s[i];
    }
    __syncthreads();
#pragma unroll
    for (int u = 0; u < 2; ++u) {
        const int cid = tid * 2 + u;
        const int d = cid >> 3, cc = cid & 7;
        union { ushort_t s[8]; uint4 u4; } ov;
#pragma unroll
        for (int jj = 0; jj < 8; ++jj) ov.s[jj] = vs[cc * 8 + jj][d];
        *(uint4*)(vt + (size_t)bh * 64 * SEQ + (size_t)d * SEQ + n0 + cc * 8) = ov.u4;
    }
}

// ---------------------------------------------------------------------------
// Flash attention, bf16 MFMA (32x32x16), swapped-QK form. bf16 msa output.
// ---------------------------------------------------------------------------
__global__ __launch_bounds__(256) void attn_kernel(const ushort_t* __restrict__ qb,
                                                   const ushort_t* __restrict__ kb,
                                                   const ushort_t* __restrict__ vt,
                                                   ushort_t* __restrict__ msa) {
    __shared__ __align__(16) char smem_raw[34816];
    uint4* kbl = (uint4*)smem_raw;
    uint4* vbl = (uint4*)(smem_raw + 16384);

    const int tid = threadIdx.x;
    const int lq = tid & 31;
    const int h  = (tid >> 5) & 1;
    const int w  = tid >> 6;
    const int bh = blockIdx.y;
    const int q0 = blockIdx.x * 128 + w * 32;

    const ushort_t* kg = kb + (size_t)bh * SEQ * 64;
    const ushort_t* vg = vt + (size_t)bh * 64 * SEQ;

    U4B qf[4];
    {
        const uint4* qrow = (const uint4*)(qb + ((size_t)bh * SEQ + q0 + lq) * 64);
#pragma unroll
        for (int s = 0; s < 4; ++s) qf[s].u = qrow[2 * s + h];
    }

    f32x16 o[2];
#pragma unroll
    for (int dc = 0; dc < 2; ++dc)
#pragma unroll
        for (int r = 0; r < 16; ++r) o[dc][r] = 0.f;
    float m_run = -INFINITY, l_run = 0.f;

    uint4 nk[2], nv[2];
    auto load_tile = [&](int t) {
#pragma unroll
        for (int u = 0; u < 2; ++u) {
            const int cid = tid * 2 + u;
            const int row = cid >> 3, c = cid & 7;
            nk[u] = *(const uint4*)(kg + (size_t)(t * 64 + row) * 64 + c * 8);
            nv[u] = *(const uint4*)(vg + (size_t)row * SEQ + t * 64 + c * 8);
        }
    };
    auto write_tile = [&](int buf) {
#pragma unroll
        for (int u = 0; u < 2; ++u) {
            const int cid = tid * 2 + u;
            const int row = cid >> 3, c = cid & 7;
            const int idx = buf * 512 + row * 8 + (c ^ (row & 7));
            kbl[idx] = nk[u];
            vbl[idx] = nv[u];
        }
    };

    load_tile(0);
    write_tile(0);

    for (int t = 0; t < SEQ / 64; ++t) {
        const int tn = (t + 1 < SEQ / 64) ? t + 1 : t;
        load_tile(tn);
        __syncthreads();
        const int bs = (t & 1) * 512;

        f32x16 st[2];
#pragma unroll
        for (int kc = 0; kc < 2; ++kc) {
#pragma unroll
            for (int r = 0; r < 16; ++r) st[kc][r] = 0.f;
#pragma unroll
            for (int s = 0; s < 4; ++s) {
                const int row = kc * 32 + lq;
                U4B ka; ka.u = kbl[bs + row * 8 + ((2 * s + h) ^ (row & 7))];
                st[kc] = MFMA(ka.b, qf[s].b, st[kc]);
            }
        }

        float pm = st[0][0];
#pragma unroll
        for (int r = 1; r < 16; ++r) pm = fmaxf(pm, st[0][r]);
#pragma unroll
        for (int r = 0; r < 16; ++r) pm = fmaxf(pm, st[1][r]);
        pm = fmaxf(pm, __shfl_xor(pm, 32));
        const float mn = fmaxf(m_run, pm);
        const float f = __expf(m_run - mn);
        m_run = mn;

        float rs = 0.f;
#pragma unroll
        for (int kc = 0; kc < 2; ++kc)
#pragma unroll
            for (int r = 0; r < 16; ++r) {
                const float p = __expf(st[kc][r] - mn);
                st[kc][r] = p;
                rs += p;
            }
        rs += __shfl_xor(rs, 32);
        l_run = l_run * f + rs;
#pragma unroll
        for (int dc = 0; dc < 2; ++dc)
#pragma unroll
            for (int r = 0; r < 16; ++r) o[dc][r] *= f;

        unsigned pk[2][8];
#pragma unroll
        for (int kc = 0; kc < 2; ++kc)
#pragma unroll
            for (int m = 0; m < 8; ++m)
                pk[kc][m] = pack2(st[kc][2 * m], st[kc][2 * m + 1]);

#pragma unroll
        for (int ks = 0; ks < 4; ++ks) {
            const int kc = ks >> 1;
            const int A0 = 4 * (ks & 1);
            const unsigned c0 = pk[kc][A0 + 0], c1 = pk[kc][A0 + 1];
            const unsigned c2 = pk[kc][A0 + 2], c3 = pk[kc][A0 + 3];
            const unsigned s0 = h ? c0 : c2;
            const unsigned s1 = h ? c1 : c3;
            const unsigned r0 = (unsigned)__shfl_xor((int)s0, 32);
            const unsigned r1 = (unsigned)__shfl_xor((int)s1, 32);
            U4B fb;
            fb.u.x = h ? r0 : c0;
            fb.u.y = h ? r1 : c1;
            fb.u.z = h ? c2 : r0;
            fb.u.w = h ? c3 : r1;
#pragma unroll
            for (int dc = 0; dc < 2; ++dc) {
                const int row = dc * 32 + lq;
                U4B va; va.u = vbl[bs + row * 8 + ((2 * ks + h) ^ (row & 7))];
                o[dc] = MFMA(va.b, fb.b, o[dc]);
            }
        }

        write_tile((t + 1) & 1);
    }

    __syncthreads();
    float* ob = (float*)smem_raw;      // [4][32][68]
    const float inv = 1.f / l_run;
#pragma unroll
    for (int dc = 0; dc < 2; ++dc)
#pragma unroll
        for (int r = 0; r < 16; ++r) {
            const int d = (r & 3) + 8 * (r >> 2) + 4 * h + 32 * dc;
            ob[(w * 32 + lq) * 68 + d] = o[dc][r] * inv;
        }
    __syncthreads();

    const int b = bh / HEADS, hh = bh % HEADS;
    const int w2 = tid >> 6, l2 = tid & 63;
    const int qr = l2 >> 1, half = (l2 & 1) * 32;
    ushort_t* dst = msa + ((size_t)(b * SEQ) + blockIdx.x * 128 + w2 * 32 + qr) * EMBED
                    + hh * 64 + half;
    const float* srcp = &ob[(w2 * 32 + qr) * 68 + half];
#pragma unroll
    for (int j = 0; j < 4; ++j) {
        union { ushort_t s[8]; uint4 u; } pv;
#pragma unroll
        for (int i = 0; i < 8; ++i) pv.s[i] = bfbits(srcp[j * 8 + i]);
        *(uint4*)(dst + j * 8) = pv.u;
    }
}

// ---------------------------------------------------------------------------
extern "C" void kernel_launch(void* const* d_in, const int* in_sizes, int n_in,
                              void* d_out, int out_size, void* d_ws, size_t ws_size,
                              hipStream_t stream) {
    const float* x     = (const float*)d_in[0];
    const float* w_qkv = (const float*)d_in[1];
    const float* b_qkv = (const float*)d_in[2];
    const float* w_lin = (const float*)d_in[3];
    const float* b_lin = (const float*)d_in[4];
    const float* g1    = (const float*)d_in[5];
    const float* be1   = (const float*)d_in[6];
    const float* g2    = (const float*)d_in[7];
    const float* be2   = (const float*)d_in[8];
    const float* w1    = (const float*)d_in[9];
    const float* b1    = (const float*)d_in[10];
    const float* w2    = (const float*)d_in[11];
    const float* b2    = (const float*)d_in[12];
    float* out = (float*)d_out;

    // workspace carve-up (~79 MB, all disjoint)
    char* wsb = (char*)d_ws;
    ushort_t* h_bf   = (ushort_t*)wsb;                      wsb += (size_t)ROWS * EMBED * 2;       // 6.29MB
    ushort_t* hid_bf = (ushort_t*)wsb;                      wsb += (size_t)ROWS * 4 * EMBED * 2;   // 25.2MB
    float*    x2     = (float*)wsb;                         wsb += (size_t)ROWS * EMBED * 4;       // 12.6MB
    ushort_t* msa_bf = (ushort_t*)wsb;                      wsb += (size_t)ROWS * EMBED * 2;       // 6.29MB
    ushort_t* qbf    = (ushort_t*)wsb;                      wsb += (size_t)BATCH * HEADS * SEQ * 64 * 2;
    ushort_t* kbf    = (ushort_t*)wsb;                      wsb += (size_t)BATCH * HEADS * SEQ * 64 * 2;
    ushort_t* vraw   = (ushort_t*)wsb;                      wsb += (size_t)BATCH * HEADS * SEQ * 64 * 2;
    ushort_t* vt     = (ushort_t*)wsb;                      wsb += (size_t)BATCH * HEADS * SEQ * 64 * 2;
    ushort_t* wqkvT  = (ushort_t*)wsb;                      wsb += (size_t)QKV_W * EMBED * 2;
    ushort_t* wlinT  = (ushort_t*)wsb;                      wsb += (size_t)EMBED * EMBED * 2;
    ushort_t* w1T    = (ushort_t*)wsb;                      wsb += (size_t)4 * EMBED * EMBED * 2;
    ushort_t* w2T    = (ushort_t*)wsb;                      wsb += (size_t)EMBED * 4 * EMBED * 2;

    // 0) weight transpose+convert
    wcvt<<<dim3(QKV_W / 32, EMBED / 32), 256, 0, stream>>>(w_qkv, wqkvT, EMBED, QKV_W);
    wcvt<<<dim3(EMBED / 32, EMBED / 32), 256, 0, stream>>>(w_lin, wlinT, EMBED, EMBED);
    wcvt<<<dim3(4 * EMBED / 32, EMBED / 32), 256, 0, stream>>>(w1, w1T, EMBED, 4 * EMBED);
    wcvt<<<dim3(EMBED / 32, 4 * EMBED / 32), 256, 0, stream>>>(w2, w2T, 4 * EMBED, EMBED);

    // 1) h = LN1(x) -> bf16
    ln_kernel<<<ROWS, 64, 0, stream>>>(x, g1, be1, h_bf);
    // 2) qkv GEMM, fused split-write into attention layouts
    gemm_bf16<0><<<dim3(ROWS / 128, QKV_W / 128), 256, 0, stream>>>(
        h_bf, wqkvT, b_qkv, nullptr, nullptr, nullptr, qbf, kbf, vraw, QKV_W, EMBED);
    // 2.5) V transpose
    vtrans<<<dim3(SEQ / 64, BATCH * HEADS), 256, 0, stream>>>(vraw, vt);
    // 3) attention -> bf16 msa
    attn_kernel<<<dim3(SEQ / 128, BATCH * HEADS), 256, 0, stream>>>(qbf, kbf, vt, msa_bf);
    // 4) x2 = msa @ w_lin + b_lin + x
    gemm_bf16<1><<<dim3(ROWS / 128, EMBED / 128), 256, 0, stream>>>(
        msa_bf, wlinT, b_lin, x, x2, nullptr, nullptr, nullptr, nullptr, EMBED, EMBED);
    // 5) h2 = LN2(x2) -> bf16
    ln_kernel<<<ROWS, 64, 0, stream>>>(x2, g2, be2, h_bf);
    // 6) hidden = gelu(h2 @ w1 + b1) -> bf16
    gemm_bf16<2><<<dim3(ROWS / 128, 4 * EMBED / 128), 256, 0, stream>>>(
        h_bf, w1T, b1, nullptr, nullptr, hid_bf, nullptr, nullptr, nullptr, 4 * EMBED, EMBED);
    // 7) out = hidden @ w2 + b2 + x2
    gemm_bf16<1><<<dim3(ROWS / 128, EMBED / 128), 256, 0, stream>>>(
        hid_bf, w2T, b2, x2, out, nullptr, nullptr, nullptr, nullptr, EMBED, 4 * EMBED);
}

// Round 4
// 285.542 us; speedup vs baseline: 4.6563x; 1.8128x over previous
//
#include <hip/hip_runtime.h>
#include <math.h>

#define EMBED 384
#define HEADS 6
#define HD    64
#define SEQ   4096
#define BATCH 2
#define ROWS  (BATCH * SEQ)   // 8192
#define QKV_W (3 * EMBED)     // 1152

typedef __bf16 bf16x8 __attribute__((ext_vector_type(8)));
typedef float  f32x16 __attribute__((ext_vector_type(16)));
typedef unsigned short ushort_t;

union U4B { uint4 u; bf16x8 b; };

#define MFMA(a, b, c) __builtin_amdgcn_mfma_f32_32x32x16_bf16(a, b, c, 0, 0, 0)

#define AS1 __attribute__((address_space(1)))
#define AS3 __attribute__((address_space(3)))

// async global->LDS, 16B per lane. LDS dest must be wave-uniform base
// (HW writes base + lane*16); global src is per-lane (pre-swizzled).
__device__ __forceinline__ void gload16(const void* g, void* l) {
    __builtin_amdgcn_global_load_lds((AS1 const unsigned int*)g,
                                     (AS3 unsigned int*)l, 16, 0, 0);
}

__device__ __forceinline__ unsigned short bfbits(float f) {
    return __builtin_bit_cast(unsigned short, (__bf16)f);
}
__device__ __forceinline__ unsigned pack2(float a, float b) {
    return ((unsigned)bfbits(b) << 16) | (unsigned)bfbits(a);
}

// ---------------------------------------------------------------------------
// LayerNorm: one wave per row of 384, bf16 output.
// ---------------------------------------------------------------------------
__global__ __launch_bounds__(64) void ln_kernel(const float* __restrict__ x,
                                                const float* __restrict__ g,
                                                const float* __restrict__ b,
                                                ushort_t* __restrict__ out) {
    const int row  = blockIdx.x;
    const int lane = threadIdx.x;
    const float* xr = x + (size_t)row * EMBED;

    float v[6];
    float sum = 0.f;
#pragma unroll
    for (int i = 0; i < 6; ++i) { v[i] = xr[lane + i * 64]; sum += v[i]; }
#pragma unroll
    for (int o = 32; o > 0; o >>= 1) sum += __shfl_xor(sum, o, 64);
    const float mu = sum * (1.f / EMBED);

    float var = 0.f;
#pragma unroll
    for (int i = 0; i < 6; ++i) { const float d = v[i] - mu; var += d * d; }
#pragma unroll
    for (int o = 32; o > 0; o >>= 1) var += __shfl_xor(var, o, 64);
    const float rstd = rsqrtf(var * (1.f / EMBED) + 1e-5f);

    ushort_t* orow = out + (size_t)row * EMBED;
#pragma unroll
    for (int i = 0; i < 6; ++i) {
        const int c = lane + i * 64;
        orow[c] = bfbits((v[i] - mu) * rstd * g[c] + b[c]);
    }
}

// ---------------------------------------------------------------------------
// All 4 weight transposes in ONE launch. W fp32 [K][N] -> Wt bf16 [N][K].
// flat blockIdx ranges: [0,432) qkv | [432,576) lin | [576,1152) w1 | rest w2
// ---------------------------------------------------------------------------
__global__ __launch_bounds__(256) void wcvt_all(const float* __restrict__ w_qkv,
                                                const float* __restrict__ w_lin,
                                                const float* __restrict__ w1,
                                                const float* __restrict__ w2,
                                                ushort_t* wqkvT, ushort_t* wlinT,
                                                ushort_t* w1T, ushort_t* w2T) {
    int bid = blockIdx.x;
    const float* W; ushort_t* Wt; int K, N, tx;
    if (bid < 432)       { W = w_qkv; Wt = wqkvT; K = 384;  N = 1152; tx = 36; }
    else if (bid < 576)  { bid -= 432;  W = w_lin; Wt = wlinT; K = 384;  N = 384;  tx = 12; }
    else if (bid < 1152) { bid -= 576;  W = w1;    Wt = w1T;   K = 384;  N = 1536; tx = 48; }
    else                 { bid -= 1152; W = w2;    Wt = w2T;   K = 1536; N = 384;  tx = 12; }
    const int nb = (bid % tx) * 32, kb = (bid / tx) * 32;

    __shared__ float ws[32][33];
    const int tid = threadIdx.x;
    {
        const int r = tid >> 3, c = (tid & 7) * 4;
        const float4 v = *(const float4*)(W + (size_t)(kb + r) * N + nb + c);
        ws[r][c] = v.x; ws[r][c + 1] = v.y; ws[r][c + 2] = v.z; ws[r][c + 3] = v.w;
    }
    __syncthreads();
    const int n = tid >> 3, k0 = (tid & 7) * 4;
    union { ushort_t s[4]; uint2 u; } o;
#pragma unroll
    for (int i = 0; i < 4; ++i) o.s[i] = bfbits(ws[k0 + i][n]);
    *(uint2*)(Wt + (size_t)(nb + n) * K + kb + k0) = o.u;
}

// ---------------------------------------------------------------------------
// bf16 MFMA GEMM, 128 x BN tile, BK=64, 4 waves, global_load_lds staging.
// Global chunk index pre-swizzled (ch^(row&7)); LDS linear; reads XOR back.
// EPI 0: QKV split-write; EPI 1: fp32 + residual; EPI 2: bf16 + exact GELU.
// ---------------------------------------------------------------------------
template <int EPI, int BN>
__global__ __launch_bounds__(256) void gemm_bf16(const ushort_t* __restrict__ A,
                                                 const ushort_t* __restrict__ Bt,
                                                 const float* __restrict__ bias,
                                                 const float* __restrict__ R,
                                                 float* __restrict__ C,
                                                 ushort_t* __restrict__ Hb,
                                                 ushort_t* __restrict__ qbp,
                                                 ushort_t* __restrict__ kbp,
                                                 ushort_t* __restrict__ vrp,
                                                 int N, int K) {
    constexpr int ACH = 1024;          // 128 rows * 8 chunks
    constexpr int BCH = BN * 8;
    constexpr int BR  = BN / 64;       // B fragments per warp
    __shared__ uint4 asl[2 * ACH];
    __shared__ uint4 bsl[2 * BCH];

    const int tid = threadIdx.x;
    const int lq = tid & 31, h = (tid >> 5) & 1, w = tid >> 6;
    const int wr = w >> 1, wc = w & 1;
    const int m0 = blockIdx.x * 128, n0 = blockIdx.y * BN;
    const int wbase = tid & 192;       // w*64 (wave-uniform)

    f32x16 acc[2][BR];
#pragma unroll
    for (int a = 0; a < 2; ++a)
#pragma unroll
        for (int b = 0; b < BR; ++b)
#pragma unroll
            for (int r = 0; r < 16; ++r) acc[a][b][r] = 0.f;

    auto stage = [&](int s, int buf) {
        const int k0 = s * 64;
#pragma unroll
        for (int u = 0; u < 4; ++u) {
            const int ci = tid + 256 * u;
            const int row = ci >> 3;
            const int chs = (ci & 7) ^ (row & 7);
            gload16((const uint4*)(A + (size_t)(m0 + row) * K + k0) + chs,
                    &asl[buf * ACH + wbase + u * 256]);
        }
#pragma unroll
        for (int u = 0; u < BN / 32; ++u) {
            const int ci = tid + 256 * u;
            const int row = ci >> 3;
            const int chs = (ci & 7) ^ (row & 7);
            gload16((const uint4*)(Bt + (size_t)(n0 + row) * K + k0) + chs,
                    &bsl[buf * BCH + wbase + u * 256]);
        }
    };

    stage(0, 0);
    const int nst = K / 64;
    for (int s = 0; s < nst; ++s) {
        __syncthreads();               // drains DMA for buf s&1; prev reads done
        if (s + 1 < nst) stage(s + 1, (s + 1) & 1);
        const int ab = (s & 1) * ACH, bb = (s & 1) * BCH;
#pragma unroll
        for (int ks = 0; ks < 4; ++ks) {
            U4B af[2], bf[BR];
#pragma unroll
            for (int a = 0; a < 2; ++a) {
                const int rm = wr * 64 + a * 32 + lq;
                af[a].u = asl[ab + rm * 8 + ((2 * ks + h) ^ (rm & 7))];
            }
#pragma unroll
            for (int b = 0; b < BR; ++b) {
                const int rn = wc * (BN / 2) + b * 32 + lq;
                bf[b].u = bsl[bb + rn * 8 + ((2 * ks + h) ^ (rn & 7))];
            }
            __builtin_amdgcn_s_setprio(1);
#pragma unroll
            for (int a = 0; a < 2; ++a)
#pragma unroll
                for (int b = 0; b < BR; ++b)
                    acc[a][b] = MFMA(af[a].b, bf[b].b, acc[a][b]);
            __builtin_amdgcn_s_setprio(0);
        }
    }

    // ---- epilogue ----
#pragma unroll
    for (int a = 0; a < 2; ++a)
#pragma unroll
        for (int b = 0; b < BR; ++b) {
            const int Cb = n0 + wc * (BN / 2) + b * 32;
            const int c = Cb + lq;
            const float bv = bias[c];
            if (EPI == 0) {
                const int head = Cb / 192, rem = Cb % 192;
                const int role = rem >> 6, d = (rem & 63) + lq;
#pragma unroll
                for (int r = 0; r < 16; ++r) {
                    const int grow = m0 + wr * 64 + a * 32 + (r & 3) + 8 * (r >> 2) + 4 * h;
                    const int bat = grow >> 12, n = grow & 4095;
                    const size_t idx = ((size_t)(bat * HEADS + head) * SEQ + n) * 64 + d;
                    const float v = acc[a][b][r] + bv;
                    if (role == 0)      qbp[idx] = bfbits(v * 0.125f);
                    else if (role == 1) kbp[idx] = bfbits(v);
                    else                vrp[idx] = bfbits(v);
                }
            } else {
#pragma unroll
                for (int r = 0; r < 16; ++r) {
                    const int row = m0 + wr * 64 + a * 32 + (r & 3) + 8 * (r >> 2) + 4 * h;
                    const float v = acc[a][b][r] + bv;
                    if (EPI == 1) {
                        C[(size_t)row * N + c] = v + R[(size_t)row * N + c];
                    } else {
                        const float gl = 0.5f * v * (1.f + erff(v * 0.70710678118654752f));
                        Hb[(size_t)row * N + c] = bfbits(gl);
                    }
                }
            }
        }
}

// ---------------------------------------------------------------------------
// V transpose: vr [bh][seq][64] bf16 -> vt [bh][64][seq] bf16
// ---------------------------------------------------------------------------
__global__ __launch_bounds__(256) void vtrans(const ushort_t* __restrict__ vr,
                                              ushort_t* __restrict__ vt) {
    __shared__ ushort_t vs[64][72];
    const int nt = blockIdx.x, bh = blockIdx.y;
    const int tid = threadIdx.x;
    const int r = tid >> 2, c0 = (tid & 3) * 16;
    const int n0 = nt * 64;
    {
        const uint4* src = (const uint4*)(vr + ((size_t)bh * SEQ + n0 + r) * 64 + c0);
        union { uint4 u[2]; ushort_t s[16]; } t2;
        t2.u[0] = src[0]; t2.u[1] = src[1];
#pragma unroll
        for (int i = 0; i < 16; ++i) vs[r][c0 + i] = t2.s[i];
    }
    __syncthreads();
#pragma unroll
    for (int u = 0; u < 2; ++u) {
        const int cid = tid * 2 + u;
        const int d = cid >> 3, cc = cid & 7;
        union { ushort_t s[8]; uint4 u4; } ov;
#pragma unroll
        for (int jj = 0; jj < 8; ++jj) ov.s[jj] = vs[cc * 8 + jj][d];
        *(uint4*)(vt + (size_t)bh * 64 * SEQ + (size_t)d * SEQ + n0 + cc * 8) = ov.u4;
    }
}

// ---------------------------------------------------------------------------
// Flash attention, bf16 MFMA, swapped-QK, KV-split x2 (blockIdx.z).
// Writes un-normalized partials: opart [z*12+bh][64 d][4096 q] fp32, ml m/l.
// ---------------------------------------------------------------------------
__global__ __launch_bounds__(256) void attn_kernel(const ushort_t* __restrict__ qb,
                                                   const ushort_t* __restrict__ kb,
                                                   const ushort_t* __restrict__ vt,
                                                   float* __restrict__ opart,
                                                   float* __restrict__ ml) {
    __shared__ uint4 kbl[1024];  // 2 bufs x 512 chunks (16B)
    __shared__ uint4 vbl[1024];

    const int tid = threadIdx.x;
    const int lq = tid & 31;
    const int h  = (tid >> 5) & 1;
    const int w  = tid >> 6;
    const int wbase = tid & 192;
    const int bh = blockIdx.y;
    const int z  = blockIdx.z;
    const int q0 = blockIdx.x * 128 + w * 32;

    const ushort_t* kg = kb + (size_t)bh * SEQ * 64;
    const ushort_t* vg = vt + (size_t)bh * 64 * SEQ;

    U4B qf[4];
    {
        const uint4* qrow = (const uint4*)(qb + ((size_t)bh * SEQ + q0 + lq) * 64);
#pragma unroll
        for (int s = 0; s < 4; ++s) qf[s].u = qrow[2 * s + h];
    }

    f32x16 o[2];
#pragma unroll
    for (int dc = 0; dc < 2; ++dc)
#pragma unroll
        for (int r = 0; r < 16; ++r) o[dc][r] = 0.f;
    float m_run = -INFINITY, l_run = 0.f;

    auto stage_tile = [&](int t, int buf) {
#pragma unroll
        for (int u = 0; u < 2; ++u) {
            const int ci = tid + 256 * u;
            const int row = ci >> 3;
            const int chs = (ci & 7) ^ (row & 7);
            gload16((const uint4*)(kg + (size_t)(t * 64 + row) * 64) + chs,
                    &kbl[buf * 512 + wbase + u * 256]);
            gload16((const uint4*)(vg + (size_t)row * SEQ + t * 64) + chs,
                    &vbl[buf * 512 + wbase + u * 256]);
        }
    };

    const int t0 = z * (SEQ / 128), t1 = t0 + SEQ / 128;   // 32 tiles per split
    stage_tile(t0, 0);

    for (int t = t0; t < t1; ++t) {
        __syncthreads();               // DMA for buf (t-t0)&1 complete
        if (t + 1 < t1) stage_tile(t + 1, (t + 1 - t0) & 1);
        const int bs = ((t - t0) & 1) * 512;

        // ---- S^T = K . Q^T ----
        f32x16 st[2];
#pragma unroll
        for (int kc = 0; kc < 2; ++kc) {
#pragma unroll
            for (int r = 0; r < 16; ++r) st[kc][r] = 0.f;
            __builtin_amdgcn_s_setprio(1);
#pragma unroll
            for (int s = 0; s < 4; ++s) {
                const int row = kc * 32 + lq;
                U4B ka; ka.u = kbl[bs + row * 8 + ((2 * s + h) ^ (row & 7))];
                st[kc] = MFMA(ka.b, qf[s].b, st[kc]);
            }
            __builtin_amdgcn_s_setprio(0);
        }

        // ---- online softmax ----
        float pm = st[0][0];
#pragma unroll
        for (int r = 1; r < 16; ++r) pm = fmaxf(pm, st[0][r]);
#pragma unroll
        for (int r = 0; r < 16; ++r) pm = fmaxf(pm, st[1][r]);
        pm = fmaxf(pm, __shfl_xor(pm, 32));
        const float mn = fmaxf(m_run, pm);
        if (__any(pm > m_run)) {       // skip-rescale: f==1 case costs nothing
            const float f = __expf(m_run - mn);
            l_run *= f;
#pragma unroll
            for (int dc = 0; dc < 2; ++dc)
#pragma unroll
                for (int r = 0; r < 16; ++r) o[dc][r] *= f;
        }
        m_run = mn;

        float rs = 0.f;
#pragma unroll
        for (int kc = 0; kc < 2; ++kc)
#pragma unroll
            for (int r = 0; r < 16; ++r) {
                const float p = __expf(st[kc][r] - mn);
                st[kc][r] = p;
                rs += p;
            }
        rs += __shfl_xor(rs, 32);
        l_run += rs;

        // ---- pack P to bf16 ----
        unsigned pk[2][8];
#pragma unroll
        for (int kc = 0; kc < 2; ++kc)
#pragma unroll
            for (int m = 0; m < 8; ++m)
                pk[kc][m] = pack2(st[kc][2 * m], st[kc][2 * m + 1]);

        // ---- O^T += V^T . P^T ----
#pragma unroll
        for (int ks = 0; ks < 4; ++ks) {
            const int kc = ks >> 1;
            const int A0 = 4 * (ks & 1);
            const unsigned c0 = pk[kc][A0 + 0], c1 = pk[kc][A0 + 1];
            const unsigned c2 = pk[kc][A0 + 2], c3 = pk[kc][A0 + 3];
            const unsigned s0 = h ? c0 : c2;
            const unsigned s1 = h ? c1 : c3;
            const unsigned r0 = (unsigned)__shfl_xor((int)s0, 32);
            const unsigned r1 = (unsigned)__shfl_xor((int)s1, 32);
            U4B fb;
            fb.u.x = h ? r0 : c0;
            fb.u.y = h ? r1 : c1;
            fb.u.z = h ? c2 : r0;
            fb.u.w = h ? c3 : r1;
            __builtin_amdgcn_s_setprio(1);
#pragma unroll
            for (int dc = 0; dc < 2; ++dc) {
                const int row = dc * 32 + lq;
                U4B va; va.u = vbl[bs + row * 8 + ((2 * ks + h) ^ (row & 7))];
                o[dc] = MFMA(va.b, fb.b, o[dc]);
            }
            __builtin_amdgcn_s_setprio(0);
        }
    }

    // ---- epilogue: un-normalized partials, coalesced [d][q] stores ----
    float* ob = opart + (size_t)(z * (BATCH * HEADS) + bh) * 64 * SEQ;
#pragma unroll
    for (int dc = 0; dc < 2; ++dc)
#pragma unroll
        for (int r = 0; r < 16; ++r) {
            const int d = (r & 3) + 8 * (r >> 2) + 4 * h + 32 * dc;
            ob[(size_t)d * SEQ + q0 + lq] = o[dc][r];
        }
    if (h == 0) {
        float* mlp = ml + (size_t)(z * (BATCH * HEADS) + bh) * 2 * SEQ;
        mlp[q0 + lq] = m_run;
        mlp[SEQ + q0 + lq] = l_run;
    }
}

// ---------------------------------------------------------------------------
// Combine the 2 KV-split partials -> bf16 msa [B][N][E]
// ---------------------------------------------------------------------------
__global__ __launch_bounds__(256) void attn_combine(const float* __restrict__ opart,
                                                    const float* __restrict__ ml,
                                                    ushort_t* __restrict__ msa) {
    const int bh = blockIdx.y;
    const int q = blockIdx.x * 64 + (threadIdx.x & 63);
    const int w = threadIdx.x >> 6;
    const float* ml0 = ml + (size_t)bh * 2 * SEQ;
    const float* ml1 = ml + (size_t)(BATCH * HEADS + bh) * 2 * SEQ;
    const float m1 = ml0[q], l1 = ml0[SEQ + q];
    const float m2 = ml1[q], l2 = ml1[SEQ + q];
    const float m = fmaxf(m1, m2);
    const float e1 = __expf(m1 - m), e2 = __expf(m2 - m);
    const float inv = 1.f / (l1 * e1 + l2 * e2);
    const float a1 = e1 * inv, a2 = e2 * inv;
    const float* o1 = opart + ((size_t)bh * 64 + w * 16) * SEQ + q;
    const float* o2 = opart + ((size_t)(BATCH * HEADS + bh) * 64 + w * 16) * SEQ + q;
    union { ushort_t s[16]; uint4 u[2]; } ov;
#pragma unroll
    for (int i = 0; i < 16; ++i)
        ov.s[i] = bfbits(o1[(size_t)i * SEQ] * a1 + o2[(size_t)i * SEQ] * a2);
    const int b = bh / HEADS, hh = bh % HEADS;
    uint4* dst = (uint4*)(msa + ((size_t)b * SEQ + q) * EMBED + hh * 64 + w * 16);
    dst[0] = ov.u[0]; dst[1] = ov.u[1];
}

// ---------------------------------------------------------------------------
extern "C" void kernel_launch(void* const* d_in, const int* in_sizes, int n_in,
                              void* d_out, int out_size, void* d_ws, size_t ws_size,
                              hipStream_t stream) {
    const float* x     = (const float*)d_in[0];
    const float* w_qkv = (const float*)d_in[1];
    const float* b_qkv = (const float*)d_in[2];
    const float* w_lin = (const float*)d_in[3];
    const float* b_lin = (const float*)d_in[4];
    const float* g1    = (const float*)d_in[5];
    const float* be1   = (const float*)d_in[6];
    const float* g2    = (const float*)d_in[7];
    const float* be2   = (const float*)d_in[8];
    const float* w1    = (const float*)d_in[9];
    const float* b1    = (const float*)d_in[10];
    const float* w2    = (const float*)d_in[11];
    const float* b2    = (const float*)d_in[12];
    float* out = (float*)d_out;

    // workspace carve-up (~79 MB)
    char* wsb = (char*)d_ws;
    ushort_t* h_bf   = (ushort_t*)wsb;  wsb += (size_t)ROWS * EMBED * 2;
    ushort_t* hid_bf = (ushort_t*)wsb;  wsb += (size_t)ROWS * 4 * EMBED * 2;   // 25.17MB
    float*    x2     = (float*)wsb;     wsb += (size_t)ROWS * EMBED * 4;
    ushort_t* msa_bf = (ushort_t*)wsb;  wsb += (size_t)ROWS * EMBED * 2;
    ushort_t* qbf    = (ushort_t*)wsb;  wsb += (size_t)BATCH * HEADS * SEQ * 64 * 2;
    ushort_t* kbf    = (ushort_t*)wsb;  wsb += (size_t)BATCH * HEADS * SEQ * 64 * 2;
    ushort_t* vraw   = (ushort_t*)wsb;  wsb += (size_t)BATCH * HEADS * SEQ * 64 * 2;
    ushort_t* vt     = (ushort_t*)wsb;  wsb += (size_t)BATCH * HEADS * SEQ * 64 * 2;
    ushort_t* wqkvT  = (ushort_t*)wsb;  wsb += (size_t)QKV_W * EMBED * 2;
    ushort_t* wlinT  = (ushort_t*)wsb;  wsb += (size_t)EMBED * EMBED * 2;
    ushort_t* w1T    = (ushort_t*)wsb;  wsb += (size_t)4 * EMBED * EMBED * 2;
    ushort_t* w2T    = (ushort_t*)wsb;  wsb += (size_t)EMBED * 4 * EMBED * 2;
    // aliases (lifetimes disjoint): attn partials live in hid_bf (25.17MB,
    // written by MLP1 later) and the head of x2 (written by proj later).
    float* opart = (float*)hid_bf;      // 2*12*64*4096*4 = 25.17MB exactly
    float* mlbuf = x2;                  // 2*12*2*4096*4  = 0.79MB

    // 0) all weight transposes, one launch
    wcvt_all<<<1728, 256, 0, stream>>>(w_qkv, w_lin, w1, w2, wqkvT, wlinT, w1T, w2T);
    // 1) h = LN1(x) -> bf16
    ln_kernel<<<ROWS, 64, 0, stream>>>(x, g1, be1, h_bf);
    // 2) qkv GEMM, fused split-write into attention layouts
    gemm_bf16<0, 128><<<dim3(ROWS / 128, QKV_W / 128), 256, 0, stream>>>(
        h_bf, wqkvT, b_qkv, nullptr, nullptr, nullptr, qbf, kbf, vraw, QKV_W, EMBED);
    // 2.5) V transpose
    vtrans<<<dim3(SEQ / 64, BATCH * HEADS), 256, 0, stream>>>(vraw, vt);
    // 3) attention (KV-split x2) -> partials, then combine -> bf16 msa
    attn_kernel<<<dim3(SEQ / 128, BATCH * HEADS, 2), 256, 0, stream>>>(
        qbf, kbf, vt, opart, mlbuf);
    attn_combine<<<dim3(SEQ / 64, BATCH * HEADS), 256, 0, stream>>>(
        opart, mlbuf, msa_bf);
    // 4) x2 = msa @ w_lin + b_lin + x   (clobbers mlbuf region - already consumed)
    gemm_bf16<1, 64><<<dim3(ROWS / 128, EMBED / 64), 256, 0, stream>>>(
        msa_bf, wlinT, b_lin, x, x2, nullptr, nullptr, nullptr, nullptr, EMBED, EMBED);
    // 5) h2 = LN2(x2) -> bf16
    ln_kernel<<<ROWS, 64, 0, stream>>>(x2, g2, be2, h_bf);
    // 6) hidden = gelu(h2 @ w1 + b1) -> bf16 (clobbers opart - already consumed)
    gemm_bf16<2, 128><<<dim3(ROWS / 128, 4 * EMBED / 128), 256, 0, stream>>>(
        h_bf, w1T, b1, nullptr, nullptr, hid_bf, nullptr, nullptr, nullptr, 4 * EMBED, EMBED);
    // 7) out = hidden @ w2 + b2 + x2
    gemm_bf16<1, 64><<<dim3(ROWS / 128, EMBED / 64), 256, 0, stream>>>(
        hid_bf, w2T, b2, x2, out, nullptr, nullptr, nullptr, nullptr, EMBED, 4 * EMBED);
}

// Round 5
// 230.996 us; speedup vs baseline: 5.7558x; 1.2361x over previous
//
#include <hip/hip_runtime.h>
#include <math.h>

#define EMBED 384
#define HEADS 6
#define HD    64
#define SEQ   4096
#define BATCH 2
#define ROWS  (BATCH * SEQ)   // 8192
#define QKV_W (3 * EMBED)     // 1152
#define NSPLIT 3              // attention KV splits

typedef __bf16 bf16x8 __attribute__((ext_vector_type(8)));
typedef float  f32x16 __attribute__((ext_vector_type(16)));
typedef unsigned short ushort_t;

union U4B { uint4 u; bf16x8 b; };

#define MFMA(a, b, c) __builtin_amdgcn_mfma_f32_32x32x16_bf16(a, b, c, 0, 0, 0)

#define AS1 __attribute__((address_space(1)))
#define AS3 __attribute__((address_space(3)))

// async global->LDS, 16B per lane. LDS dest is wave-uniform base
// (HW writes base + lane*16); global src is per-lane (pre-swizzled).
__device__ __forceinline__ void gload16(const void* g, void* l) {
    __builtin_amdgcn_global_load_lds((AS1 const unsigned int*)g,
                                     (AS3 unsigned int*)l, 16, 0, 0);
}

__device__ __forceinline__ unsigned short bfbits(float f) {
    return __builtin_bit_cast(unsigned short, (__bf16)f);
}
__device__ __forceinline__ unsigned pack2(float a, float b) {
    return ((unsigned)bfbits(b) << 16) | (unsigned)bfbits(a);
}
__device__ __forceinline__ float max3f(float a, float b, float c) {
    return fmaxf(fmaxf(a, b), c);   // fuses to v_max3_f32
}
__device__ __forceinline__ float ex2(float x) {
    return __builtin_amdgcn_exp2f(x);
}

// ---------------------------------------------------------------------------
// LayerNorm: one wave per row of 384, bf16 output.
// ---------------------------------------------------------------------------
__global__ __launch_bounds__(64) void ln_kernel(const float* __restrict__ x,
                                                const float* __restrict__ g,
                                                const float* __restrict__ b,
                                                ushort_t* __restrict__ out) {
    const int row  = blockIdx.x;
    const int lane = threadIdx.x;
    const float* xr = x + (size_t)row * EMBED;

    float v[6];
    float sum = 0.f;
#pragma unroll
    for (int i = 0; i < 6; ++i) { v[i] = xr[lane + i * 64]; sum += v[i]; }
#pragma unroll
    for (int o = 32; o > 0; o >>= 1) sum += __shfl_xor(sum, o, 64);
    const float mu = sum * (1.f / EMBED);

    float var = 0.f;
#pragma unroll
    for (int i = 0; i < 6; ++i) { const float d = v[i] - mu; var += d * d; }
#pragma unroll
    for (int o = 32; o > 0; o >>= 1) var += __shfl_xor(var, o, 64);
    const float rstd = rsqrtf(var * (1.f / EMBED) + 1e-5f);

    ushort_t* orow = out + (size_t)row * EMBED;
#pragma unroll
    for (int i = 0; i < 6; ++i) {
        const int c = lane + i * 64;
        orow[c] = bfbits((v[i] - mu) * rstd * g[c] + b[c]);
    }
}

// ---------------------------------------------------------------------------
// All 4 weight transposes in ONE launch. W fp32 [K][N] -> Wt bf16 [N][K].
// ---------------------------------------------------------------------------
__global__ __launch_bounds__(256) void wcvt_all(const float* __restrict__ w_qkv,
                                                const float* __restrict__ w_lin,
                                                const float* __restrict__ w1,
                                                const float* __restrict__ w2,
                                                ushort_t* wqkvT, ushort_t* wlinT,
                                                ushort_t* w1T, ushort_t* w2T) {
    int bid = blockIdx.x;
    const float* W; ushort_t* Wt; int K, N, tx;
    if (bid < 432)       { W = w_qkv; Wt = wqkvT; K = 384;  N = 1152; tx = 36; }
    else if (bid < 576)  { bid -= 432;  W = w_lin; Wt = wlinT; K = 384;  N = 384;  tx = 12; }
    else if (bid < 1152) { bid -= 576;  W = w1;    Wt = w1T;   K = 384;  N = 1536; tx = 48; }
    else                 { bid -= 1152; W = w2;    Wt = w2T;   K = 1536; N = 384;  tx = 12; }
    const int nb = (bid % tx) * 32, kb = (bid / tx) * 32;

    __shared__ float ws[32][33];
    const int tid = threadIdx.x;
    {
        const int r = tid >> 3, c = (tid & 7) * 4;
        const float4 v = *(const float4*)(W + (size_t)(kb + r) * N + nb + c);
        ws[r][c] = v.x; ws[r][c + 1] = v.y; ws[r][c + 2] = v.z; ws[r][c + 3] = v.w;
    }
    __syncthreads();
    const int n = tid >> 3, k0 = (tid & 7) * 4;
    union { ushort_t s[4]; uint2 u; } o;
#pragma unroll
    for (int i = 0; i < 4; ++i) o.s[i] = bfbits(ws[k0 + i][n]);
    *(uint2*)(Wt + (size_t)(nb + n) * K + kb + k0) = o.u;
}

// ---------------------------------------------------------------------------
// bf16 MFMA GEMM, BM x BN tile, BK=64, 4 waves (2x2), global_load_lds staging.
// EPI 0: QKV split-write (q in exp2 domain); EPI 1: fp32 + residual;
// EPI 2: bf16 + exact GELU.
// ---------------------------------------------------------------------------
template <int EPI, int BM, int BN>
__global__ __launch_bounds__(256) void gemm_bf16(const ushort_t* __restrict__ A,
                                                 const ushort_t* __restrict__ Bt,
                                                 const float* __restrict__ bias,
                                                 const float* __restrict__ R,
                                                 float* __restrict__ C,
                                                 ushort_t* __restrict__ Hb,
                                                 ushort_t* __restrict__ qbp,
                                                 ushort_t* __restrict__ kbp,
                                                 ushort_t* __restrict__ vrp,
                                                 int N, int K) {
    constexpr int ACH = BM * 8;        // uint4 chunks per buffer
    constexpr int BCH = BN * 8;
    constexpr int AR  = BM / 64;       // A fragments per warp
    constexpr int BR  = BN / 64;       // B fragments per warp
    __shared__ uint4 asl[2 * ACH];
    __shared__ uint4 bsl[2 * BCH];

    const int tid = threadIdx.x;
    const int lq = tid & 31, h = (tid >> 5) & 1, w = tid >> 6;
    const int wr = w >> 1, wc = w & 1;
    const int m0 = blockIdx.x * BM, n0 = blockIdx.y * BN;
    const int wbase = tid & 192;       // w*64 (wave-uniform)

    f32x16 acc[AR][BR];
#pragma unroll
    for (int a = 0; a < AR; ++a)
#pragma unroll
        for (int b = 0; b < BR; ++b)
#pragma unroll
            for (int r = 0; r < 16; ++r) acc[a][b][r] = 0.f;

    auto stage = [&](int s, int buf) {
        const int k0 = s * 64;
#pragma unroll
        for (int u = 0; u < BM / 32; ++u) {
            const int ci = tid + 256 * u;
            const int row = ci >> 3;
            const int chs = (ci & 7) ^ (row & 7);
            gload16((const uint4*)(A + (size_t)(m0 + row) * K + k0) + chs,
                    &asl[buf * ACH + wbase + u * 256]);
        }
#pragma unroll
        for (int u = 0; u < BN / 32; ++u) {
            const int ci = tid + 256 * u;
            const int row = ci >> 3;
            const int chs = (ci & 7) ^ (row & 7);
            gload16((const uint4*)(Bt + (size_t)(n0 + row) * K + k0) + chs,
                    &bsl[buf * BCH + wbase + u * 256]);
        }
    };

    stage(0, 0);
    const int nst = K / 64;
    for (int s = 0; s < nst; ++s) {
        __syncthreads();               // drains DMA for buf s&1
        if (s + 1 < nst) stage(s + 1, (s + 1) & 1);
        const int ab = (s & 1) * ACH, bb = (s & 1) * BCH;
#pragma unroll
        for (int ks = 0; ks < 4; ++ks) {
            U4B af[AR], bf[BR];
#pragma unroll
            for (int a = 0; a < AR; ++a) {
                const int rm = wr * (BM / 2) + a * 32 + lq;
                af[a].u = asl[ab + rm * 8 + ((2 * ks + h) ^ (rm & 7))];
            }
#pragma unroll
            for (int b = 0; b < BR; ++b) {
                const int rn = wc * (BN / 2) + b * 32 + lq;
                bf[b].u = bsl[bb + rn * 8 + ((2 * ks + h) ^ (rn & 7))];
            }
            __builtin_amdgcn_s_setprio(1);
#pragma unroll
            for (int a = 0; a < AR; ++a)
#pragma unroll
                for (int b = 0; b < BR; ++b)
                    acc[a][b] = MFMA(af[a].b, bf[b].b, acc[a][b]);
            __builtin_amdgcn_s_setprio(0);
        }
    }

    // ---- epilogue ----
#pragma unroll
    for (int a = 0; a < AR; ++a)
#pragma unroll
        for (int b = 0; b < BR; ++b) {
            const int Cb = n0 + wc * (BN / 2) + b * 32;
            const int c = Cb + lq;
            const float bv = bias[c];
            if (EPI == 0) {
                const int head = Cb / 192, rem = Cb % 192;
                const int role = rem >> 6, d = (rem & 63) + lq;
#pragma unroll
                for (int r = 0; r < 16; ++r) {
                    const int grow = m0 + wr * (BM / 2) + a * 32 + (r & 3) + 8 * (r >> 2) + 4 * h;
                    const int bat = grow >> 12, n = grow & 4095;
                    const size_t idx = ((size_t)(bat * HEADS + head) * SEQ + n) * 64 + d;
                    const float v = acc[a][b][r] + bv;
                    // q scaled by 1/sqrt(64) * log2(e) -> exp2 softmax domain
                    if (role == 0)      qbp[idx] = bfbits(v * 0.1803368801f);
                    else if (role == 1) kbp[idx] = bfbits(v);
                    else                vrp[idx] = bfbits(v);
                }
            } else {
#pragma unroll
                for (int r = 0; r < 16; ++r) {
                    const int row = m0 + wr * (BM / 2) + a * 32 + (r & 3) + 8 * (r >> 2) + 4 * h;
                    const float v = acc[a][b][r] + bv;
                    if (EPI == 1) {
                        C[(size_t)row * N + c] = v + R[(size_t)row * N + c];
                    } else {
                        const float gl = 0.5f * v * (1.f + erff(v * 0.70710678118654752f));
                        Hb[(size_t)row * N + c] = bfbits(gl);
                    }
                }
            }
        }
}

// ---------------------------------------------------------------------------
// V transpose: vr [bh][seq][64] bf16 -> vt [bh][64][seq] bf16
// ---------------------------------------------------------------------------
__global__ __launch_bounds__(256) void vtrans(const ushort_t* __restrict__ vr,
                                              ushort_t* __restrict__ vt) {
    __shared__ ushort_t vs[64][72];
    const int nt = blockIdx.x, bh = blockIdx.y;
    const int tid = threadIdx.x;
    const int r = tid >> 2, c0 = (tid & 3) * 16;
    const int n0 = nt * 64;
    {
        const uint4* src = (const uint4*)(vr + ((size_t)bh * SEQ + n0 + r) * 64 + c0);
        union { uint4 u[2]; ushort_t s[16]; } t2;
        t2.u[0] = src[0]; t2.u[1] = src[1];
#pragma unroll
        for (int i = 0; i < 16; ++i) vs[r][c0 + i] = t2.s[i];
    }
    __syncthreads();
#pragma unroll
    for (int u = 0; u < 2; ++u) {
        const int cid = tid * 2 + u;
        const int d = cid >> 3, cc = cid & 7;
        union { ushort_t s[8]; uint4 u4; } ov;
#pragma unroll
        for (int jj = 0; jj < 8; ++jj) ov.s[jj] = vs[cc * 8 + jj][d];
        *(uint4*)(vt + (size_t)bh * 64 * SEQ + (size_t)d * SEQ + n0 + cc * 8) = ov.u4;
    }
}

// ---------------------------------------------------------------------------
// Flash attention, bf16 MFMA, swapped-QK, exp2 domain, KV-split x NSPLIT.
// Defer-max (THR=8 in log2 units) + permlane32_swap P-fragment assembly.
// ---------------------------------------------------------------------------
__global__ __launch_bounds__(256) void attn_kernel(const ushort_t* __restrict__ qb,
                                                   const ushort_t* __restrict__ kb,
                                                   const ushort_t* __restrict__ vt,
                                                   float* __restrict__ opart,
                                                   float* __restrict__ ml) {
    __shared__ uint4 kbl[1024];  // 2 bufs x 512 chunks (16B)
    __shared__ uint4 vbl[1024];

    const int tid = threadIdx.x;
    const int lq = tid & 31;
    const int h  = (tid >> 5) & 1;
    const int w  = tid >> 6;
    const int wbase = tid & 192;
    const int bh = blockIdx.y;
    const int z  = blockIdx.z;
    const int q0 = blockIdx.x * 128 + w * 32;

    const ushort_t* kg = kb + (size_t)bh * SEQ * 64;
    const ushort_t* vg = vt + (size_t)bh * 64 * SEQ;

    U4B qf[4];
    {
        const uint4* qrow = (const uint4*)(qb + ((size_t)bh * SEQ + q0 + lq) * 64);
#pragma unroll
        for (int s = 0; s < 4; ++s) qf[s].u = qrow[2 * s + h];
    }

    f32x16 o[2];
#pragma unroll
    for (int dc = 0; dc < 2; ++dc)
#pragma unroll
        for (int r = 0; r < 16; ++r) o[dc][r] = 0.f;
    float m_run = -INFINITY, l_run = 0.f;

    auto stage_tile = [&](int t, int buf) {
#pragma unroll
        for (int u = 0; u < 2; ++u) {
            const int ci = tid + 256 * u;
            const int row = ci >> 3;
            const int chs = (ci & 7) ^ (row & 7);
            gload16((const uint4*)(kg + (size_t)(t * 64 + row) * 64) + chs,
                    &kbl[buf * 512 + wbase + u * 256]);
            gload16((const uint4*)(vg + (size_t)row * SEQ + t * 64) + chs,
                    &vbl[buf * 512 + wbase + u * 256]);
        }
    };

    const int t0 = z * 11;                         // splits: 11 / 11 / 10 tiles
    const int t1 = min(t0 + 11, SEQ / 128);
    stage_tile(t0, 0);

    for (int t = t0; t < t1; ++t) {
        __syncthreads();               // DMA for buf (t-t0)&1 complete
        if (t + 1 < t1) stage_tile(t + 1, (t + 1 - t0) & 1);
        const int bs = ((t - t0) & 1) * 512;

        // ---- S^T = K . Q^T  (log2-domain scores) ----
        f32x16 st[2];
#pragma unroll
        for (int kc = 0; kc < 2; ++kc) {
#pragma unroll
            for (int r = 0; r < 16; ++r) st[kc][r] = 0.f;
            __builtin_amdgcn_s_setprio(1);
#pragma unroll
            for (int s = 0; s < 4; ++s) {
                const int row = kc * 32 + lq;
                U4B ka; ka.u = kbl[bs + row * 8 + ((2 * s + h) ^ (row & 7))];
                st[kc] = MFMA(ka.b, qf[s].b, st[kc]);
            }
            __builtin_amdgcn_s_setprio(0);
        }

        // ---- tile max via max3 tree ----
#define SV(i) st[(i) >> 4][(i) & 15]
        float r3[11];
#pragma unroll
        for (int i = 0; i < 10; ++i) r3[i] = max3f(SV(3 * i), SV(3 * i + 1), SV(3 * i + 2));
        r3[10] = fmaxf(SV(30), SV(31));
        const float s1a = max3f(r3[0], r3[1], r3[2]);
        const float s1b = max3f(r3[3], r3[4], r3[5]);
        const float s1c = max3f(r3[6], r3[7], r3[8]);
        const float s1d = fmaxf(r3[9], r3[10]);
        float pm = fmaxf(max3f(s1a, s1b, s1c), s1d);
#undef SV
        pm = fmaxf(pm, __shfl_xor(pm, 32));

        // ---- defer-max: rescale only when max grew by > 8 (log2) ----
        if (__any(pm - m_run > 8.f)) {
            const float mn = fmaxf(m_run, pm);
            const float f = ex2(m_run - mn);
            l_run *= f;
#pragma unroll
            for (int dc = 0; dc < 2; ++dc)
#pragma unroll
                for (int r = 0; r < 16; ++r) o[dc][r] *= f;
            m_run = mn;
        }

        float rs = 0.f;
#pragma unroll
        for (int kc = 0; kc < 2; ++kc)
#pragma unroll
            for (int r = 0; r < 16; ++r) {
                const float p = ex2(st[kc][r] - m_run);   // <= 2^8
                st[kc][r] = p;
                rs += p;
            }
        rs += __shfl_xor(rs, 32);
        l_run += rs;

        // ---- pack P to bf16 ----
        unsigned pk[2][8];
#pragma unroll
        for (int kc = 0; kc < 2; ++kc)
#pragma unroll
            for (int m = 0; m < 8; ++m)
                pk[kc][m] = pack2(st[kc][2 * m], st[kc][2 * m + 1]);

        // ---- O^T += V^T . P^T (fragment exchange via permlane32_swap) ----
#pragma unroll
        for (int ks = 0; ks < 4; ++ks) {
            const int kc = ks >> 1;
            const int A0 = 4 * (ks & 1);
            const unsigned c0 = pk[kc][A0 + 0], c1 = pk[kc][A0 + 1];
            const unsigned c2 = pk[kc][A0 + 2], c3 = pk[kc][A0 + 3];
            auto r02 = __builtin_amdgcn_permlane32_swap((int)c0, (int)c2, false, false);
            auto r13 = __builtin_amdgcn_permlane32_swap((int)c1, (int)c3, false, false);
            U4B fb;
            fb.u.x = (unsigned)r02[0];
            fb.u.y = (unsigned)r13[0];
            fb.u.z = (unsigned)r02[1];
            fb.u.w = (unsigned)r13[1];
            __builtin_amdgcn_s_setprio(1);
#pragma unroll
            for (int dc = 0; dc < 2; ++dc) {
                const int row = dc * 32 + lq;
                U4B va; va.u = vbl[bs + row * 8 + ((2 * ks + h) ^ (row & 7))];
                o[dc] = MFMA(va.b, fb.b, o[dc]);
            }
            __builtin_amdgcn_s_setprio(0);
        }
    }

    // ---- epilogue: un-normalized partials, coalesced [d][q] stores ----
    float* ob = opart + (size_t)(z * (BATCH * HEADS) + bh) * 64 * SEQ;
#pragma unroll
    for (int dc = 0; dc < 2; ++dc)
#pragma unroll
        for (int r = 0; r < 16; ++r) {
            const int d = (r & 3) + 8 * (r >> 2) + 4 * h + 32 * dc;
            ob[(size_t)d * SEQ + q0 + lq] = o[dc][r];
        }
    if (h == 0) {
        float* mlp = ml + (size_t)(z * (BATCH * HEADS) + bh) * 2 * SEQ;
        mlp[q0 + lq] = m_run;
        mlp[SEQ + q0 + lq] = l_run;
    }
}

// ---------------------------------------------------------------------------
// Combine NSPLIT KV-split partials -> bf16 msa [B][N][E] (log2-domain m)
// ---------------------------------------------------------------------------
__global__ __launch_bounds__(256) void attn_combine(const float* __restrict__ opart,
                                                    const float* __restrict__ ml,
                                                    ushort_t* __restrict__ msa) {
    const int bh = blockIdx.y;
    const int q = blockIdx.x * 64 + (threadIdx.x & 63);
    const int w = threadIdx.x >> 6;
    float m[NSPLIT], l[NSPLIT];
#pragma unroll
    for (int z = 0; z < NSPLIT; ++z) {
        const float* mlz = ml + (size_t)(z * (BATCH * HEADS) + bh) * 2 * SEQ;
        m[z] = mlz[q]; l[z] = mlz[SEQ + q];
    }
    const float mm = max3f(m[0], m[1], m[2]);
    float e[NSPLIT], lt = 0.f;
#pragma unroll
    for (int z = 0; z < NSPLIT; ++z) { e[z] = ex2(m[z] - mm); lt += l[z] * e[z]; }
    const float inv = 1.f / lt;
#pragma unroll
    for (int z = 0; z < NSPLIT; ++z) e[z] *= inv;

    union { ushort_t s[16]; uint4 u[2]; } ov;
#pragma unroll
    for (int i = 0; i < 16; ++i) {
        float acc = 0.f;
#pragma unroll
        for (int z = 0; z < NSPLIT; ++z)
            acc += opart[((size_t)(z * (BATCH * HEADS) + bh) * 64 + w * 16 + i) * SEQ + q] * e[z];
        ov.s[i] = bfbits(acc);
    }
    const int b = bh / HEADS, hh = bh % HEADS;
    uint4* dst = (uint4*)(msa + ((size_t)b * SEQ + q) * EMBED + hh * 64 + w * 16);
    dst[0] = ov.u[0]; dst[1] = ov.u[1];
}

// ---------------------------------------------------------------------------
extern "C" void kernel_launch(void* const* d_in, const int* in_sizes, int n_in,
                              void* d_out, int out_size, void* d_ws, size_t ws_size,
                              hipStream_t stream) {
    const float* x     = (const float*)d_in[0];
    const float* w_qkv = (const float*)d_in[1];
    const float* b_qkv = (const float*)d_in[2];
    const float* w_lin = (const float*)d_in[3];
    const float* b_lin = (const float*)d_in[4];
    const float* g1    = (const float*)d_in[5];
    const float* be1   = (const float*)d_in[6];
    const float* g2    = (const float*)d_in[7];
    const float* be2   = (const float*)d_in[8];
    const float* w1    = (const float*)d_in[9];
    const float* b1    = (const float*)d_in[10];
    const float* w2    = (const float*)d_in[11];
    const float* b2    = (const float*)d_in[12];
    float* out = (float*)d_out;

    // workspace carve-up (~80.2 MB)
    char* wsb = (char*)d_ws;
    ushort_t* h_bf   = (ushort_t*)wsb;  wsb += (size_t)ROWS * EMBED * 2;       // 6.29MB
    ushort_t* hid_bf = (ushort_t*)wsb;  wsb += (size_t)ROWS * 4 * EMBED * 2;   // 25.17MB
    float*    x2     = (float*)wsb;     wsb += (size_t)ROWS * EMBED * 4;       // 12.58MB
    ushort_t* msa_bf = (ushort_t*)wsb;  wsb += (size_t)ROWS * EMBED * 2;
    ushort_t* qbf    = (ushort_t*)wsb;  wsb += (size_t)BATCH * HEADS * SEQ * 64 * 2;
    ushort_t* kbf    = (ushort_t*)wsb;  wsb += (size_t)BATCH * HEADS * SEQ * 64 * 2;
    ushort_t* vraw   = (ushort_t*)wsb;  wsb += (size_t)BATCH * HEADS * SEQ * 64 * 2;
    ushort_t* vt     = (ushort_t*)wsb;  wsb += (size_t)BATCH * HEADS * SEQ * 64 * 2;
    ushort_t* wqkvT  = (ushort_t*)wsb;  wsb += (size_t)QKV_W * EMBED * 2;
    ushort_t* wlinT  = (ushort_t*)wsb;  wsb += (size_t)EMBED * EMBED * 2;
    ushort_t* w1T    = (ushort_t*)wsb;  wsb += (size_t)4 * EMBED * EMBED * 2;
    ushort_t* w2T    = (ushort_t*)wsb;  wsb += (size_t)EMBED * 4 * EMBED * 2;
    float*    mlbuf  = (float*)wsb;     wsb += (size_t)NSPLIT * BATCH * HEADS * 2 * SEQ * 4;
    // opart (3 x 12.58MB = 37.75MB) aliases the CONTIGUOUS hid_bf + x2 region
    // (both dead during attention; rewritten by MLP1 / proj afterwards).
    float* opart = (float*)hid_bf;

    // 0) all weight transposes, one launch
    wcvt_all<<<1728, 256, 0, stream>>>(w_qkv, w_lin, w1, w2, wqkvT, wlinT, w1T, w2T);
    // 1) h = LN1(x) -> bf16
    ln_kernel<<<ROWS, 64, 0, stream>>>(x, g1, be1, h_bf);
    // 2) qkv GEMM, fused split-write into attention layouts (q in exp2 domain)
    gemm_bf16<0, 64, 128><<<dim3(ROWS / 64, QKV_W / 128), 256, 0, stream>>>(
        h_bf, wqkvT, b_qkv, nullptr, nullptr, nullptr, qbf, kbf, vraw, QKV_W, EMBED);
    // 2.5) V transpose
    vtrans<<<dim3(SEQ / 64, BATCH * HEADS), 256, 0, stream>>>(vraw, vt);
    // 3) attention (KV-split x3) -> partials, then combine -> bf16 msa
    attn_kernel<<<dim3(SEQ / 128, BATCH * HEADS, NSPLIT), 256, 0, stream>>>(
        qbf, kbf, vt, opart, mlbuf);
    attn_combine<<<dim3(SEQ / 64, BATCH * HEADS), 256, 0, stream>>>(
        opart, mlbuf, msa_bf);
    // 4) x2 = msa @ w_lin + b_lin + x
    gemm_bf16<1, 64, 64><<<dim3(ROWS / 64, EMBED / 64), 256, 0, stream>>>(
        msa_bf, wlinT, b_lin, x, x2, nullptr, nullptr, nullptr, nullptr, EMBED, EMBED);
    // 5) h2 = LN2(x2) -> bf16
    ln_kernel<<<ROWS, 64, 0, stream>>>(x2, g2, be2, h_bf);
    // 6) hidden = gelu(h2 @ w1 + b1) -> bf16 (clobbers opart head - consumed)
    gemm_bf16<2, 64, 128><<<dim3(ROWS / 64, 4 * EMBED / 128), 256, 0, stream>>>(
        h_bf, w1T, b1, nullptr, nullptr, hid_bf, nullptr, nullptr, nullptr, 4 * EMBED, EMBED);
    // 7) out = hidden @ w2 + b2 + x2
    gemm_bf16<1, 64, 64><<<dim3(ROWS / 64, EMBED / 64), 256, 0, stream>>>(
        hid_bf, w2T, b2, x2, out, nullptr, nullptr, nullptr, nullptr, EMBED, 4 * EMBED);
}